// Round 1
// baseline (1164.643 us; speedup 1.0000x reference)
//
#include <hip/hip_runtime.h>
#include <math.h>

#define BB 2
#define TT 2048
#define DD 1024
#define NHEAD 16
#define HDIM 64
#define MM (BB*TT)          // 4096
#define NHNH (NHEAD*HDIM)   // 1024

#define LOG2E_F 1.442695041f
#define NEGINF_F (-1.0e9f)

// ---------------------------------------------------------------------------
// QKV projection GEMM: Out[b][n][t][h] = (sum_d X[bt][d]*W[d][nh] + bias[nh]) * colscale(h)
// A = X [4096 x 1024] row-major, B = W [1024 x 1024] row-major.
// 64x64 block tile, BK=16, 256 threads, 4x4 microtile.
// ---------------------------------------------------------------------------
__global__ __launch_bounds__(256)
void qkv_gemm(const float* __restrict__ X, const float* __restrict__ W,
              const float* __restrict__ bias, const float* __restrict__ pds,
              float* __restrict__ Out)
{
    __shared__ float AsT[16][64];   // [k][m]
    __shared__ float Bs[16][64];    // [k][n]
    const int tid  = threadIdx.x;
    const int brow = blockIdx.y << 6;
    const int bcol = blockIdx.x << 6;

    const int aRow = tid >> 2;
    const int aC4  = (tid & 3) << 2;
    const int bRow = tid >> 4;
    const int bC4  = (tid & 15) << 2;

    const float* Ap = X + (size_t)(brow + aRow) * DD + aC4;
    const float* Bp = W + (size_t)bRow * NHNH + bcol + bC4;

    const int tx = tid & 15, ty = tid >> 4;
    const int r0 = ty << 2, c0 = tx << 2;

    float acc[4][4];
    #pragma unroll
    for (int i = 0; i < 4; ++i)
        #pragma unroll
        for (int j = 0; j < 4; ++j) acc[i][j] = 0.f;

    for (int k0 = 0; k0 < DD; k0 += 16) {
        float4 av = *(const float4*)(Ap + k0);
        float4 bv = *(const float4*)(Bp + (size_t)k0 * NHNH);
        __syncthreads();
        AsT[aC4+0][aRow] = av.x;
        AsT[aC4+1][aRow] = av.y;
        AsT[aC4+2][aRow] = av.z;
        AsT[aC4+3][aRow] = av.w;
        *(float4*)&Bs[bRow][bC4] = bv;
        __syncthreads();
        #pragma unroll
        for (int k = 0; k < 16; ++k) {
            float4 a = *(const float4*)&AsT[k][r0];
            float4 b = *(const float4*)&Bs[k][c0];
            acc[0][0] += a.x*b.x; acc[0][1] += a.x*b.y; acc[0][2] += a.x*b.z; acc[0][3] += a.x*b.w;
            acc[1][0] += a.y*b.x; acc[1][1] += a.y*b.y; acc[1][2] += a.y*b.z; acc[1][3] += a.y*b.w;
            acc[2][0] += a.z*b.x; acc[2][1] += a.z*b.y; acc[2][2] += a.z*b.z; acc[2][3] += a.z*b.w;
            acc[3][0] += a.w*b.x; acc[3][1] += a.w*b.y; acc[3][2] += a.w*b.z; acc[3][3] += a.w*b.w;
        }
    }

    // epilogue: bias, optional per-dim scale, write to [B][N][T][H]
    float cs[4], bb[4];
    #pragma unroll
    for (int j = 0; j < 4; ++j) {
        int col = bcol + c0 + j;
        int h = col & (HDIM-1);
        float s = 1.f;
        if (pds) {
            float x = pds[h];
            float sp = fmaxf(x, 0.f) + log1pf(expf(-fabsf(x)));  // softplus
            s = (LOG2E_F / 8.0f) * sp;   // sqrt(H) = 8
        }
        cs[j] = s;
        bb[j] = bias[col];
    }
    const int colbase = bcol + c0;
    const int n  = colbase >> 6;
    const int h0 = colbase & (HDIM-1);
    #pragma unroll
    for (int i = 0; i < 4; ++i) {
        int row  = brow + r0 + i;
        int bidx = row >> 11;         // T = 2048
        int t    = row & (TT-1);
        float4 o;
        o.x = (acc[i][0] + bb[0]) * cs[0];
        o.y = (acc[i][1] + bb[1]) * cs[1];
        o.z = (acc[i][2] + bb[2]) * cs[2];
        o.w = (acc[i][3] + bb[3]) * cs[3];
        *(float4*)(Out + ((((size_t)bidx*NHEAD + n)*TT + t)*HDIM + h0)) = o;
    }
}

// ---------------------------------------------------------------------------
// Flash attention: per block (b, n, 64 q-rows); K/V tiles of 64.
// Q is pre-scaled. mask==0 -> -1e9 before softmax.
// AO output layout: [B*T][N*H]
// ---------------------------------------------------------------------------
__global__ __launch_bounds__(256)
void attn_kernel(const float* __restrict__ Q, const float* __restrict__ K,
                 const float* __restrict__ V, const int* __restrict__ mask,
                 float* __restrict__ AO)
{
    __shared__ float QsT[64][64];  // [d][r]
    __shared__ float KsT[64][64];  // [d][k]
    __shared__ float Vs[64][64];   // [k][h]
    __shared__ float Ps[64][64];   // [r][k]

    const int tid   = threadIdx.x;
    const int bn    = blockIdx.y;          // b*N + n
    const int b     = bn >> 4;
    const int n     = bn & 15;
    const int qbase = blockIdx.x << 6;

    const float* Qb = Q + (size_t)bn * TT * HDIM;
    const float* Kb = K + (size_t)bn * TT * HDIM;
    const float* Vb = V + (size_t)bn * TT * HDIM;
    const int* mrow = mask + (size_t)b * TT * TT;

    const int sRow = tid >> 2;
    const int sC4  = (tid & 3) << 2;

    // stage Q tile transposed
    #pragma unroll
    for (int pass = 0; pass < 4; ++pass) {
        int c = sC4 + pass * 16;
        float4 v = *(const float4*)(Qb + (size_t)(qbase + sRow) * HDIM + c);
        QsT[c+0][sRow] = v.x; QsT[c+1][sRow] = v.y;
        QsT[c+2][sRow] = v.z; QsT[c+3][sRow] = v.w;
    }

    const int tx = tid & 15, ty = tid >> 4;
    const int r0 = ty << 2, c0 = tx << 2;

    float O[4][4];
    #pragma unroll
    for (int i = 0; i < 4; ++i)
        #pragma unroll
        for (int j = 0; j < 4; ++j) O[i][j] = 0.f;
    float m_i[4] = {-INFINITY, -INFINITY, -INFINITY, -INFINITY};
    float l_i[4] = {0.f, 0.f, 0.f, 0.f};

    for (int kb = 0; kb < TT; kb += 64) {
        __syncthreads();   // previous tile fully consumed (also covers Q staging)
        // stage K transposed + V direct
        #pragma unroll
        for (int pass = 0; pass < 4; ++pass) {
            int c = sC4 + pass * 16;
            float4 kv = *(const float4*)(Kb + (size_t)(kb + sRow) * HDIM + c);
            KsT[c+0][sRow] = kv.x; KsT[c+1][sRow] = kv.y;
            KsT[c+2][sRow] = kv.z; KsT[c+3][sRow] = kv.w;
            float4 vv = *(const float4*)(Vb + (size_t)(kb + sRow) * HDIM + c);
            *(float4*)&Vs[sRow][c] = vv;
        }
        __syncthreads();

        // phase 1: S tile = Q K^T
        float s[4][4];
        #pragma unroll
        for (int i = 0; i < 4; ++i)
            #pragma unroll
            for (int j = 0; j < 4; ++j) s[i][j] = 0.f;
        for (int d = 0; d < 64; ++d) {
            float4 a  = *(const float4*)&QsT[d][r0];
            float4 b4 = *(const float4*)&KsT[d][c0];
            s[0][0] += a.x*b4.x; s[0][1] += a.x*b4.y; s[0][2] += a.x*b4.z; s[0][3] += a.x*b4.w;
            s[1][0] += a.y*b4.x; s[1][1] += a.y*b4.y; s[1][2] += a.y*b4.z; s[1][3] += a.y*b4.w;
            s[2][0] += a.z*b4.x; s[2][1] += a.z*b4.y; s[2][2] += a.z*b4.z; s[2][3] += a.z*b4.w;
            s[3][0] += a.w*b4.x; s[3][1] += a.w*b4.y; s[3][2] += a.w*b4.z; s[3][3] += a.w*b4.w;
        }

        // mask + online softmax (rows live in 16-lane groups -> shuffle reduce)
        #pragma unroll
        for (int i = 0; i < 4; ++i) {
            const int q = qbase + r0 + i;
            int4 mm = *(const int4*)(mrow + (size_t)q * TT + kb + c0);
            if (mm.x == 0) s[i][0] = NEGINF_F;
            if (mm.y == 0) s[i][1] = NEGINF_F;
            if (mm.z == 0) s[i][2] = NEGINF_F;
            if (mm.w == 0) s[i][3] = NEGINF_F;
            float mx = fmaxf(fmaxf(s[i][0], s[i][1]), fmaxf(s[i][2], s[i][3]));
            mx = fmaxf(mx, __shfl_xor(mx, 1));
            mx = fmaxf(mx, __shfl_xor(mx, 2));
            mx = fmaxf(mx, __shfl_xor(mx, 4));
            mx = fmaxf(mx, __shfl_xor(mx, 8));
            const float mnew  = fmaxf(m_i[i], mx);
            const float alpha = expf(m_i[i] - mnew);   // exp(-inf)=0 on first tile
            float p0 = expf(s[i][0] - mnew);
            float p1 = expf(s[i][1] - mnew);
            float p2 = expf(s[i][2] - mnew);
            float p3 = expf(s[i][3] - mnew);
            float sum = (p0 + p1) + (p2 + p3);
            sum += __shfl_xor(sum, 1);
            sum += __shfl_xor(sum, 2);
            sum += __shfl_xor(sum, 4);
            sum += __shfl_xor(sum, 8);
            l_i[i] = l_i[i] * alpha + sum;
            m_i[i] = mnew;
            O[i][0] *= alpha; O[i][1] *= alpha; O[i][2] *= alpha; O[i][3] *= alpha;
            float4 pv; pv.x = p0; pv.y = p1; pv.z = p2; pv.w = p3;
            *(float4*)&Ps[r0+i][c0] = pv;
        }
        __syncthreads();

        // phase 2: O += P * V   (thread cols h0 = c0)
        for (int k = 0; k < 64; ++k) {
            float4 vv = *(const float4*)&Vs[k][c0];
            float p0 = Ps[r0+0][k];
            float p1 = Ps[r0+1][k];
            float p2 = Ps[r0+2][k];
            float p3 = Ps[r0+3][k];
            O[0][0] += p0*vv.x; O[0][1] += p0*vv.y; O[0][2] += p0*vv.z; O[0][3] += p0*vv.w;
            O[1][0] += p1*vv.x; O[1][1] += p1*vv.y; O[1][2] += p1*vv.z; O[1][3] += p1*vv.w;
            O[2][0] += p2*vv.x; O[2][1] += p2*vv.y; O[2][2] += p2*vv.z; O[2][3] += p2*vv.w;
            O[3][0] += p3*vv.x; O[3][1] += p3*vv.y; O[3][2] += p3*vv.z; O[3][3] += p3*vv.w;
        }
    }

    // normalize and write AO[b*T + q][n*64 + h]
    #pragma unroll
    for (int i = 0; i < 4; ++i) {
        float inv = 1.0f / l_i[i];
        int q = qbase + r0 + i;
        size_t row = (size_t)b * TT + q;
        float4 o;
        o.x = O[i][0]*inv; o.y = O[i][1]*inv; o.z = O[i][2]*inv; o.w = O[i][3]*inv;
        *(float4*)(AO + row * NHNH + (size_t)n * HDIM + c0) = o;
    }
}

// ---------------------------------------------------------------------------
// Output projection: Out[bt][d] = sum_j AO[bt][j] * Wo[d][j] + bo[d]
// A row-major, B accessed transposed (both contract on inner dim).
// ---------------------------------------------------------------------------
__global__ __launch_bounds__(256)
void out_gemm(const float* __restrict__ A, const float* __restrict__ Wo,
              const float* __restrict__ bo, float* __restrict__ Out)
{
    __shared__ float AsT[16][64];   // [k][m]
    __shared__ float BsT[16][64];   // [k][d]
    const int tid  = threadIdx.x;
    const int brow = blockIdx.y << 6;
    const int bcol = blockIdx.x << 6;

    const int aRow = tid >> 2;
    const int aC4  = (tid & 3) << 2;

    const float* Ap = A  + (size_t)(brow + aRow) * NHNH + aC4;
    const float* Bp = Wo + (size_t)(bcol + aRow) * NHNH + aC4;

    const int tx = tid & 15, ty = tid >> 4;
    const int r0 = ty << 2, c0 = tx << 2;

    float acc[4][4];
    #pragma unroll
    for (int i = 0; i < 4; ++i)
        #pragma unroll
        for (int j = 0; j < 4; ++j) acc[i][j] = 0.f;

    for (int k0 = 0; k0 < NHNH; k0 += 16) {
        float4 av = *(const float4*)(Ap + k0);
        float4 bv = *(const float4*)(Bp + k0);
        __syncthreads();
        AsT[aC4+0][aRow] = av.x;
        AsT[aC4+1][aRow] = av.y;
        AsT[aC4+2][aRow] = av.z;
        AsT[aC4+3][aRow] = av.w;
        BsT[aC4+0][aRow] = bv.x;
        BsT[aC4+1][aRow] = bv.y;
        BsT[aC4+2][aRow] = bv.z;
        BsT[aC4+3][aRow] = bv.w;
        __syncthreads();
        #pragma unroll
        for (int k = 0; k < 16; ++k) {
            float4 a = *(const float4*)&AsT[k][r0];
            float4 b = *(const float4*)&BsT[k][c0];
            acc[0][0] += a.x*b.x; acc[0][1] += a.x*b.y; acc[0][2] += a.x*b.z; acc[0][3] += a.x*b.w;
            acc[1][0] += a.y*b.x; acc[1][1] += a.y*b.y; acc[1][2] += a.y*b.z; acc[1][3] += a.y*b.w;
            acc[2][0] += a.z*b.x; acc[2][1] += a.z*b.y; acc[2][2] += a.z*b.z; acc[2][3] += a.z*b.w;
            acc[3][0] += a.w*b.x; acc[3][1] += a.w*b.y; acc[3][2] += a.w*b.z; acc[3][3] += a.w*b.w;
        }
    }

    #pragma unroll
    for (int i = 0; i < 4; ++i) {
        int row = brow + r0 + i;
        int col = bcol + c0;
        float4 o;
        o.x = acc[i][0] + bo[col+0];
        o.y = acc[i][1] + bo[col+1];
        o.z = acc[i][2] + bo[col+2];
        o.w = acc[i][3] + bo[col+3];
        *(float4*)(Out + (size_t)row * DD + col) = o;
    }
}

// ---------------------------------------------------------------------------
extern "C" void kernel_launch(void* const* d_in, const int* in_sizes, int n_in,
                              void* d_out, int out_size, void* d_ws, size_t ws_size,
                              hipStream_t stream)
{
    const float* X   = (const float*)d_in[0];
    const int*   msk = (const int*)d_in[1];
    const float* wq  = (const float*)d_in[2];
    const float* bq  = (const float*)d_in[3];
    const float* wk  = (const float*)d_in[4];
    const float* bk  = (const float*)d_in[5];
    const float* wv  = (const float*)d_in[6];
    const float* bv  = (const float*)d_in[7];
    const float* wo  = (const float*)d_in[8];
    const float* bo  = (const float*)d_in[9];
    const float* pds = (const float*)d_in[10];
    float* out = (float*)d_out;

    float* ws = (float*)d_ws;
    float* Qb = ws;                  // [B][N][T][H]  4194304 floats
    float* Kb = ws + 4194304;
    float* Vb = ws + 8388608;
    float* AO = ws + 12582912;       // [B*T][N*H]

    dim3 blk(256);
    dim3 gp(NHNH/64, MM/64);         // (16, 64)
    qkv_gemm<<<gp, blk, 0, stream>>>(X, wq, bq, pds, Qb);
    qkv_gemm<<<gp, blk, 0, stream>>>(X, wk, bk, nullptr, Kb);
    qkv_gemm<<<gp, blk, 0, stream>>>(X, wv, bv, nullptr, Vb);

    dim3 ga(TT/64, BB*NHEAD);        // (32, 32)
    attn_kernel<<<ga, blk, 0, stream>>>(Qb, Kb, Vb, msk, AO);

    dim3 go(DD/64, MM/64);           // (16, 64)
    out_gemm<<<go, blk, 0, stream>>>(AO, wo, bo, out);
}

// Round 3
// 460.164 us; speedup vs baseline: 2.5309x; 2.5309x over previous
//
#include <hip/hip_runtime.h>
#include <math.h>

typedef __bf16 bf16;
typedef __attribute__((ext_vector_type(8))) __bf16 bf16x8;
typedef __attribute__((ext_vector_type(4))) __bf16 bf16x4;
typedef __attribute__((ext_vector_type(4))) float f32x4;

#define BB 2
#define TT 2048
#define DD 1024
#define NHD 16
#define HD 64
#define MM (BB*TT)          // 4096
#define LOG2E_F 1.442695041f
#define NEGINF_F (-1.0e9f)

// ---------------------------------------------------------------------------
// fp32 -> bf16 convert (plain)
// ---------------------------------------------------------------------------
__global__ __launch_bounds__(256)
void cvt_bf16(const float* __restrict__ in, bf16* __restrict__ out, int n4)
{
    int i = blockIdx.x * 256 + threadIdx.x;
    if (i < n4) {
        float4 v = ((const float4*)in)[i];
        bf16x4 o = { (bf16)v.x, (bf16)v.y, (bf16)v.z, (bf16)v.w };
        *(bf16x4*)(out + (size_t)i * 4) = o;
    }
}

// ---------------------------------------------------------------------------
// fp32 [1024 d][1024 nh] -> bf16 hi/lo [nh][d] transpose + split-convert
// ---------------------------------------------------------------------------
__global__ __launch_bounds__(256)
void cvt_transpose_split(const float* __restrict__ in, bf16* __restrict__ outH,
                         bf16* __restrict__ outL, const int do_lo)
{
    __shared__ float tile[32][33];
    const int t  = threadIdx.x;
    const int r  = t >> 3;
    const int c4 = (t & 7) << 2;
    const int bx = blockIdx.x << 5;   // nh block
    const int by = blockIdx.y << 5;   // d block
    float4 v = *(const float4*)(in + (size_t)(by + r) * 1024 + bx + c4);
    tile[r][c4+0] = v.x; tile[r][c4+1] = v.y; tile[r][c4+2] = v.z; tile[r][c4+3] = v.w;
    __syncthreads();
    bf16x4 hv, lv;
    #pragma unroll
    for (int j = 0; j < 4; ++j) {
        float f = tile[c4 + j][r];
        bf16 h = (bf16)f;
        hv[j] = h;
        lv[j] = (bf16)(f - (float)h);
    }
    *(bf16x4*)(outH + (size_t)(bx + r) * 1024 + by + c4) = hv;
    if (do_lo)
        *(bf16x4*)(outL + (size_t)(bx + r) * 1024 + by + c4) = lv;
}

// ---------------------------------------------------------------------------
// int32 mask -> bitmask via 64-lane ballot
// ---------------------------------------------------------------------------
__global__ __launch_bounds__(256)
void pack_mask(const int* __restrict__ m, unsigned* __restrict__ bits, int n)
{
    int i = blockIdx.x * 256 + threadIdx.x;
    int lane = threadIdx.x & 63;
    int v = (i < n) ? m[i] : 0;
    unsigned long long b = __ballot(v != 0);
    if ((lane & 31) == 0 && i < n)
        bits[i >> 5] = (unsigned)(b >> (lane & 32));
}

// ---------------------------------------------------------------------------
// Unified MFMA GEMM: C[m][n] = sum_k A[m][k] * Bt[n][k]
//   A source: Af32 (fp32, split to hi/lo in-register) or Abf (bf16 single)
//   prec=1: acc = Ah*Bh + Ah*Bl + Al*Bh (fp32-accurate); prec=0: Ah*Bh only
//   mode 0: scattered [B][N][T][H] split hi/lo out, val=(acc+bias[col])*scale(h)
//   mode 1: scattered [B][N][T][H] single bf16, val=acc+bias[col]
//   mode 2: flat fp32 [m][1024], val=acc+bias[col]
// 64x64 tile, BK=32, 4 waves (2x2 of 32x32).
// ---------------------------------------------------------------------------
__global__ __launch_bounds__(256)
void gemm_mfma(const float* __restrict__ Af32, const bf16* __restrict__ Abf,
               const bf16* __restrict__ Bh, const bf16* __restrict__ Bl,
               const float* __restrict__ bias, const float* __restrict__ pds,
               bf16* __restrict__ outH, bf16* __restrict__ outL,
               float* __restrict__ outF, const int mode, const int prec)
{
    __shared__ bf16 Ash[64][40];
    __shared__ bf16 Asl[64][40];
    __shared__ bf16 Bsh[64][40];
    __shared__ bf16 Bsl[64][40];

    const int t    = threadIdx.x;
    const int lane = t & 63;
    const int w    = t >> 6;
    const int quad = lane >> 4, l15 = lane & 15;
    const int wm   = (w >> 1) << 5;
    const int wn   = (w & 1)  << 5;
    const int m0   = blockIdx.y << 6;
    const int n0   = blockIdx.x << 6;

    const int sr = t >> 2;          // 0..63
    const int sc = (t & 3) << 3;    // 0,8,16,24

    f32x4 acc[2][2];
    #pragma unroll
    for (int i = 0; i < 2; ++i)
        #pragma unroll
        for (int j = 0; j < 2; ++j) acc[i][j] = (f32x4){0.f,0.f,0.f,0.f};

    for (int k0 = 0; k0 < DD; k0 += 32) {
        bf16x8 avh, avl, bvh, bvl;
        if (Af32) {
            const float* ap = Af32 + (size_t)(m0 + sr) * DD + k0 + sc;
            float4 f0 = *(const float4*)ap;
            float4 f1 = *(const float4*)(ap + 4);
            float fv[8] = {f0.x, f0.y, f0.z, f0.w, f1.x, f1.y, f1.z, f1.w};
            #pragma unroll
            for (int j = 0; j < 8; ++j) {
                bf16 h = (bf16)fv[j];
                avh[j] = h;
                avl[j] = (bf16)(fv[j] - (float)h);
            }
        } else {
            avh = *(const bf16x8*)(Abf + (size_t)(m0 + sr) * DD + k0 + sc);
        }
        bvh = *(const bf16x8*)(Bh + (size_t)(n0 + sr) * DD + k0 + sc);
        if (prec) bvl = *(const bf16x8*)(Bl + (size_t)(n0 + sr) * DD + k0 + sc);

        __syncthreads();
        *(bf16x8*)&Ash[sr][sc] = avh;
        *(bf16x8*)&Bsh[sr][sc] = bvh;
        if (prec) {
            *(bf16x8*)&Asl[sr][sc] = avl;
            *(bf16x8*)&Bsl[sr][sc] = bvl;
        }
        __syncthreads();

        bf16x8 ah[2], al[2], bh[2], bl[2];
        #pragma unroll
        for (int mt = 0; mt < 2; ++mt)
            ah[mt] = *(const bf16x8*)&Ash[wm + (mt << 4) + l15][quad << 3];
        #pragma unroll
        for (int nt = 0; nt < 2; ++nt)
            bh[nt] = *(const bf16x8*)&Bsh[wn + (nt << 4) + l15][quad << 3];
        if (prec) {
            #pragma unroll
            for (int mt = 0; mt < 2; ++mt)
                al[mt] = *(const bf16x8*)&Asl[wm + (mt << 4) + l15][quad << 3];
            #pragma unroll
            for (int nt = 0; nt < 2; ++nt)
                bl[nt] = *(const bf16x8*)&Bsl[wn + (nt << 4) + l15][quad << 3];
        }

        #pragma unroll
        for (int mt = 0; mt < 2; ++mt)
            #pragma unroll
            for (int nt = 0; nt < 2; ++nt) {
                acc[mt][nt] = __builtin_amdgcn_mfma_f32_16x16x32_bf16(
                    ah[mt], bh[nt], acc[mt][nt], 0, 0, 0);
                if (prec) {
                    acc[mt][nt] = __builtin_amdgcn_mfma_f32_16x16x32_bf16(
                        ah[mt], bl[nt], acc[mt][nt], 0, 0, 0);
                    acc[mt][nt] = __builtin_amdgcn_mfma_f32_16x16x32_bf16(
                        al[mt], bh[nt], acc[mt][nt], 0, 0, 0);
                }
            }
    }

    #pragma unroll
    for (int nt = 0; nt < 2; ++nt) {
        const int col = n0 + wn + (nt << 4) + l15;
        const float bcol = bias[col];
        float s = 1.f;
        if (pds) {
            const int h = col & 63;
            float x = pds[h];
            float sp = fmaxf(x, 0.f) + log1pf(expf(-fabsf(x)));  // softplus
            s = (LOG2E_F / 8.0f) * sp;                            // sqrt(64)=8
        }
        #pragma unroll
        for (int mt = 0; mt < 2; ++mt) {
            #pragma unroll
            for (int reg = 0; reg < 4; ++reg) {
                const int row = m0 + wm + (mt << 4) + (quad << 2) + reg;
                float val = (acc[mt][nt][reg] + bcol) * s;
                if (mode == 2) {
                    outF[(size_t)row * DD + col] = val;
                } else {
                    const int n  = col >> 6, h = col & 63;
                    const int bi = row >> 11;
                    const int tt = row & (TT - 1);
                    const size_t idx = (((size_t)bi * NHD + n) * TT + tt) * HD + h;
                    if (mode == 0) {
                        bf16 hi = (bf16)val;
                        outH[idx] = hi;
                        outL[idx] = (bf16)(val - (float)hi);
                    } else {
                        outH[idx] = (bf16)val;
                    }
                }
            }
        }
    }
}

// ---------------------------------------------------------------------------
// MFMA flash attention with split-bf16 Q,K (fp32-accurate scores).
// Block = (b, n, 64 q rows); 4 waves x 16 q rows; K-tiles of 64.
// ---------------------------------------------------------------------------
__global__ __launch_bounds__(256)
void attn_mfma(const bf16* __restrict__ Qh, const bf16* __restrict__ Ql,
               const bf16* __restrict__ Kh, const bf16* __restrict__ Kl,
               const bf16* __restrict__ V, const unsigned* __restrict__ mbits,
               bf16* __restrict__ AO)
{
    __shared__ bf16 Qsh[64][72];
    __shared__ bf16 Qsl[64][72];
    __shared__ bf16 Ksh[64][72];
    __shared__ bf16 Ksl[64][72];
    __shared__ bf16 Vts[64][72];       // [h][s]
    __shared__ bf16 Ps[4][16][72];     // per-wave P tile [q][s]
    __shared__ unsigned msk[64][2];

    const int t    = threadIdx.x;
    const int lane = t & 63;
    const int w    = t >> 6;
    const int quad = lane >> 4, l15 = lane & 15;
    const int bn   = blockIdx.y;
    const int b    = bn >> 4, n = bn & 15;
    const int q0   = blockIdx.x << 6;

    const bf16* Qbh = Qh + (size_t)bn * TT * HD;
    const bf16* Qbl = Ql + (size_t)bn * TT * HD;
    const bf16* Kbh = Kh + (size_t)bn * TT * HD;
    const bf16* Kbl = Kl + (size_t)bn * TT * HD;
    const bf16* Vb  = V  + (size_t)bn * TT * HD;

    // stage Q tile (hi+lo) once
    {
        const int r = t >> 2, c = (t & 3) << 4;
        const bf16* ph = Qbh + (size_t)(q0 + r) * HD + c;
        const bf16* pl = Qbl + (size_t)(q0 + r) * HD + c;
        *(bf16x8*)&Qsh[r][c]     = *(const bf16x8*)ph;
        *(bf16x8*)&Qsh[r][c + 8] = *(const bf16x8*)(ph + 8);
        *(bf16x8*)&Qsl[r][c]     = *(const bf16x8*)pl;
        *(bf16x8*)&Qsl[r][c + 8] = *(const bf16x8*)(pl + 8);
    }

    f32x4 O[4];
    #pragma unroll
    for (int i = 0; i < 4; ++i) O[i] = (f32x4){0.f,0.f,0.f,0.f};
    float m_i[4] = {-INFINITY, -INFINITY, -INFINITY, -INFINITY};
    float l_i[4] = {0.f, 0.f, 0.f, 0.f};

    const int rK = t >> 2,  cK = (t & 3) << 4;
    const int rV = t & 63,  cV = (t >> 6) << 4;

    for (int kb = 0; kb < TT; kb += 64) {
        // prefetch globals
        const bf16* kph = Kbh + (size_t)(kb + rK) * HD + cK;
        const bf16* kpl = Kbl + (size_t)(kb + rK) * HD + cK;
        bf16x8 kh0 = *(const bf16x8*)kph;
        bf16x8 kh1 = *(const bf16x8*)(kph + 8);
        bf16x8 kl0 = *(const bf16x8*)kpl;
        bf16x8 kl1 = *(const bf16x8*)(kpl + 8);
        const bf16* vp = Vb + (size_t)(kb + rV) * HD + cV;
        bf16x8 v0v = *(const bf16x8*)vp;
        bf16x8 v1v = *(const bf16x8*)(vp + 8);
        unsigned mw = 0;
        if (t < 128)
            mw = mbits[((size_t)b * TT + q0 + (t >> 1)) * (TT / 32) + (kb >> 5) + (t & 1)];

        __syncthreads();   // previous tile fully consumed (covers Q staging too)
        *(bf16x8*)&Ksh[rK][cK]     = kh0;
        *(bf16x8*)&Ksh[rK][cK + 8] = kh1;
        *(bf16x8*)&Ksl[rK][cK]     = kl0;
        *(bf16x8*)&Ksl[rK][cK + 8] = kl1;
        #pragma unroll
        for (int j = 0; j < 8; ++j) {
            Vts[cV + j][rV]     = v0v[j];
            Vts[cV + 8 + j][rV] = v1v[j];
        }
        if (t < 128) msk[t >> 1][t & 1] = mw;
        __syncthreads();

        // S = Q K^T with split precision: Qh*Kh + Qh*Kl + Ql*Kh
        f32x4 s_acc[4];
        #pragma unroll
        for (int i = 0; i < 4; ++i) s_acc[i] = (f32x4){0.f,0.f,0.f,0.f};
        #pragma unroll
        for (int k2 = 0; k2 < 2; ++k2) {
            bf16x8 aqh = *(const bf16x8*)&Qsh[(w << 4) + l15][(k2 << 5) + (quad << 3)];
            bf16x8 aql = *(const bf16x8*)&Qsl[(w << 4) + l15][(k2 << 5) + (quad << 3)];
            #pragma unroll
            for (int nt = 0; nt < 4; ++nt) {
                bf16x8 bkh = *(const bf16x8*)&Ksh[(nt << 4) + l15][(k2 << 5) + (quad << 3)];
                bf16x8 bkl = *(const bf16x8*)&Ksl[(nt << 4) + l15][(k2 << 5) + (quad << 3)];
                s_acc[nt] = __builtin_amdgcn_mfma_f32_16x16x32_bf16(aqh, bkh, s_acc[nt], 0, 0, 0);
                s_acc[nt] = __builtin_amdgcn_mfma_f32_16x16x32_bf16(aqh, bkl, s_acc[nt], 0, 0, 0);
                s_acc[nt] = __builtin_amdgcn_mfma_f32_16x16x32_bf16(aql, bkh, s_acc[nt], 0, 0, 0);
            }
        }

        // mask + online softmax; write P (bf16) to per-wave LDS
        #pragma unroll
        for (int reg = 0; reg < 4; ++reg) {
            const int rowb = (w << 4) + (quad << 2) + reg;
            const unsigned w0 = msk[rowb][0], w1 = msk[rowb][1];
            float sv[4];
            #pragma unroll
            for (int nt = 0; nt < 4; ++nt) {
                const unsigned word = (nt < 2) ? w0 : w1;
                const int bit = ((nt & 1) << 4) + l15;
                sv[nt] = ((word >> bit) & 1u) ? s_acc[nt][reg] : NEGINF_F;
            }
            float mx = fmaxf(fmaxf(sv[0], sv[1]), fmaxf(sv[2], sv[3]));
            mx = fmaxf(mx, __shfl_xor(mx, 1));
            mx = fmaxf(mx, __shfl_xor(mx, 2));
            mx = fmaxf(mx, __shfl_xor(mx, 4));
            mx = fmaxf(mx, __shfl_xor(mx, 8));
            const float mnew  = fmaxf(m_i[reg], mx);
            const float alpha = __expf(m_i[reg] - mnew);
            float p[4], sum = 0.f;
            #pragma unroll
            for (int nt = 0; nt < 4; ++nt) { p[nt] = __expf(sv[nt] - mnew); sum += p[nt]; }
            sum += __shfl_xor(sum, 1);
            sum += __shfl_xor(sum, 2);
            sum += __shfl_xor(sum, 4);
            sum += __shfl_xor(sum, 8);
            l_i[reg] = l_i[reg] * alpha + sum;
            m_i[reg] = mnew;
            #pragma unroll
            for (int nt = 0; nt < 4; ++nt) {
                O[nt][reg] *= alpha;
                Ps[w][(quad << 2) + reg][(nt << 4) + l15] = (bf16)p[nt];
            }
        }

        // O += P V
        #pragma unroll
        for (int s2 = 0; s2 < 2; ++s2) {
            bf16x8 ap = *(const bf16x8*)&Ps[w][l15][(s2 << 5) + (quad << 3)];
            #pragma unroll
            for (int nt = 0; nt < 4; ++nt) {
                bf16x8 bv = *(const bf16x8*)&Vts[(nt << 4) + l15][(s2 << 5) + (quad << 3)];
                O[nt] = __builtin_amdgcn_mfma_f32_16x16x32_bf16(ap, bv, O[nt], 0, 0, 0);
            }
        }
    }

    // normalize + write AO (bf16, [B*T][N*H])
    #pragma unroll
    for (int reg = 0; reg < 4; ++reg) {
        const float inv = 1.0f / l_i[reg];
        const int q = q0 + (w << 4) + (quad << 2) + reg;
        const size_t base = ((size_t)b * TT + q) * (NHD * HD) + (size_t)n * HD;
        #pragma unroll
        for (int nt = 0; nt < 4; ++nt)
            AO[base + (nt << 4) + l15] = (bf16)(O[nt][reg] * inv);
    }
}

// ---------------------------------------------------------------------------
extern "C" void kernel_launch(void* const* d_in, const int* in_sizes, int n_in,
                              void* d_out, int out_size, void* d_ws, size_t ws_size,
                              hipStream_t stream)
{
    const float* X   = (const float*)d_in[0];
    const int*   msk = (const int*)d_in[1];
    const float* wq  = (const float*)d_in[2];
    const float* bq  = (const float*)d_in[3];
    const float* wk  = (const float*)d_in[4];
    const float* bk  = (const float*)d_in[5];
    const float* wv  = (const float*)d_in[6];
    const float* bv  = (const float*)d_in[7];
    const float* wo  = (const float*)d_in[8];
    const float* bo  = (const float*)d_in[9];
    const float* pds = (const float*)d_in[10];
    float* out = (float*)d_out;

    bf16* ws  = (bf16*)d_ws;
    bf16* Wqh = ws;                      // 1048576 each
    bf16* Wql = ws + 1048576;
    bf16* Wkh = ws + 2097152;
    bf16* Wkl = ws + 3145728;
    bf16* Wvh = ws + 4194304;
    bf16* Wob = ws + 5242880;
    bf16* Qhb = ws + 6291456;            // 4194304 each, [B][N][T][H]
    bf16* Qlb = ws + 10485760;
    bf16* Khb = ws + 14680064;
    bf16* Klb = ws + 18874368;
    bf16* Vb  = ws + 23068672;
    unsigned* mbits = (unsigned*)(ws + 27262976);  // 262144 words
    bf16* AOb = ws;                      // alias Wqh..Wkl (dead after projections)

    dim3 blk(256);

    cvt_transpose_split<<<dim3(32, 32), blk, 0, stream>>>(wq, Wqh, Wql, 1);
    cvt_transpose_split<<<dim3(32, 32), blk, 0, stream>>>(wk, Wkh, Wkl, 1);
    cvt_transpose_split<<<dim3(32, 32), blk, 0, stream>>>(wv, Wvh, Wvh, 0);
    cvt_bf16<<<1024, blk, 0, stream>>>(wo, Wob, DD * NHD * HD / 4);
    pack_mask<<<32768, blk, 0, stream>>>(msk, mbits, BB * TT * TT);

    dim3 gp(16, 64);   // N/64, M/64
    gemm_mfma<<<gp, blk, 0, stream>>>(X, nullptr, Wqh, Wql, bq, pds,
                                      Qhb, Qlb, nullptr, 0, 1);
    gemm_mfma<<<gp, blk, 0, stream>>>(X, nullptr, Wkh, Wkl, bk, nullptr,
                                      Khb, Klb, nullptr, 0, 1);
    gemm_mfma<<<gp, blk, 0, stream>>>(X, nullptr, Wvh, nullptr, bv, nullptr,
                                      Vb, nullptr, nullptr, 1, 0);

    dim3 ga(TT / 64, BB * NHD);   // (32, 32)
    attn_mfma<<<ga, blk, 0, stream>>>(Qhb, Qlb, Khb, Klb, Vb, mbits, AOb);

    gemm_mfma<<<gp, blk, 0, stream>>>(nullptr, AOb, Wob, nullptr, bo, nullptr,
                                      nullptr, nullptr, out, 2, 0);
}

// Round 5
// 404.461 us; speedup vs baseline: 2.8795x; 1.1377x over previous
//
#include <hip/hip_runtime.h>
#include <math.h>

typedef __bf16 bf16;
typedef __attribute__((ext_vector_type(8))) __bf16 bf16x8;
typedef __attribute__((ext_vector_type(4))) __bf16 bf16x4;
typedef __attribute__((ext_vector_type(4))) float f32x4;

#define BB 2
#define TT 2048
#define DD 1024
#define NHD 16
#define HD 64
#define MM (BB*TT)          // 4096
#define LOG2E_F 1.442695041f
#define NEGINF_F (-1.0e9f)

// async global->LDS, 16B per lane; LDS dest must be wave-uniform base
__device__ __forceinline__ void gld16(const bf16* g, bf16* l)
{
    __builtin_amdgcn_global_load_lds(
        (const __attribute__((address_space(1))) unsigned int*)g,
        (__attribute__((address_space(3))) unsigned int*)l, 16, 0, 0);
}

// ---------------------------------------------------------------------------
// fp32 -> bf16 hi/lo split (elementwise)
// ---------------------------------------------------------------------------
__global__ __launch_bounds__(256)
void split_x(const float* __restrict__ in, bf16* __restrict__ hi,
             bf16* __restrict__ lo, int n4)
{
    int i = blockIdx.x * 256 + threadIdx.x;
    if (i < n4) {
        float4 v = ((const float4*)in)[i];
        float f[4] = {v.x, v.y, v.z, v.w};
        bf16x4 h, l;
        #pragma unroll
        for (int j = 0; j < 4; ++j) {
            bf16 hh = (bf16)f[j];
            h[j] = hh;
            l[j] = (bf16)(f[j] - (float)hh);
        }
        *(bf16x4*)(hi + (size_t)i * 4) = h;
        *(bf16x4*)(lo + (size_t)i * 4) = l;
    }
}

// ---------------------------------------------------------------------------
// fp32 -> bf16 convert (plain)
// ---------------------------------------------------------------------------
__global__ __launch_bounds__(256)
void cvt_bf16(const float* __restrict__ in, bf16* __restrict__ out, int n4)
{
    int i = blockIdx.x * 256 + threadIdx.x;
    if (i < n4) {
        float4 v = ((const float4*)in)[i];
        bf16x4 o = { (bf16)v.x, (bf16)v.y, (bf16)v.z, (bf16)v.w };
        *(bf16x4*)(out + (size_t)i * 4) = o;
    }
}

// ---------------------------------------------------------------------------
// fp32 [1024 d][1024 nh] -> bf16 hi/lo [nh][d] transpose + split-convert
// ---------------------------------------------------------------------------
__global__ __launch_bounds__(256)
void cvt_transpose_split(const float* __restrict__ in, bf16* __restrict__ outH,
                         bf16* __restrict__ outL, const int do_lo)
{
    __shared__ float tile[32][33];
    const int t  = threadIdx.x;
    const int r  = t >> 3;
    const int c4 = (t & 7) << 2;
    const int bx = blockIdx.x << 5;   // nh block
    const int by = blockIdx.y << 5;   // d block
    float4 v = *(const float4*)(in + (size_t)(by + r) * 1024 + bx + c4);
    tile[r][c4+0] = v.x; tile[r][c4+1] = v.y; tile[r][c4+2] = v.z; tile[r][c4+3] = v.w;
    __syncthreads();
    bf16x4 hv, lv;
    #pragma unroll
    for (int j = 0; j < 4; ++j) {
        float f = tile[c4 + j][r];
        bf16 h = (bf16)f;
        hv[j] = h;
        lv[j] = (bf16)(f - (float)h);
    }
    *(bf16x4*)(outH + (size_t)(bx + r) * 1024 + by + c4) = hv;
    if (do_lo)
        *(bf16x4*)(outL + (size_t)(bx + r) * 1024 + by + c4) = lv;
}

// ---------------------------------------------------------------------------
// int32 mask -> bitmask via 64-lane ballot
// ---------------------------------------------------------------------------
__global__ __launch_bounds__(256)
void pack_mask(const int* __restrict__ m, unsigned* __restrict__ bits, int n)
{
    int i = blockIdx.x * 256 + threadIdx.x;
    int lane = threadIdx.x & 63;
    int v = (i < n) ? m[i] : 0;
    unsigned long long b = __ballot(v != 0);
    if ((lane & 31) == 0 && i < n)
        bits[i >> 5] = (unsigned)(b >> (lane & 32));
}

// ---------------------------------------------------------------------------
// m97-style 128x128 MFMA GEMM, BK=32, global_load_lds staging, segmented K.
// C[m][n] = sum_seg sum_k Aseg[m][k] * Bseg[n][k]   (all operands [rows][1024])
// mode 0: QK-proj epilogue — col<1024: Q (scale, split hi/lo to [b,n,t,h]);
//         col>=1024: K (split hi/lo).  bias1=bq, bias2=bk.
//         Q scale = (LOG2E^2/8)*softplus — extra LOG2E converts the softmax
//         to exp2 domain (reference: e^(LOG2E*qk) == 2^(LOG2E^2*qk)).
// mode 1: Vt epilogue — rows=nh, cols=bt; out[b*1024+row][t] bf16; bias1[row].
// mode 2: plain fp32 out[row*1024+col] + bias2[col].
// ---------------------------------------------------------------------------
__global__ __launch_bounds__(256)
void gemm128(const bf16* __restrict__ A0, const bf16* __restrict__ A1,
             const bf16* __restrict__ A2, const bf16* __restrict__ B0,
             const bf16* __restrict__ B1, const bf16* __restrict__ B2,
             const int nseg,
             const float* __restrict__ bias1, const float* __restrict__ bias2,
             const float* __restrict__ pds,
             bf16* __restrict__ oQh, bf16* __restrict__ oQl,
             bf16* __restrict__ oKh, bf16* __restrict__ oKl,
             bf16* __restrict__ oVt, float* __restrict__ oF,
             const int mode)
{
    __shared__ bf16 As[128 * 32];
    __shared__ bf16 Bs[128 * 32];

    const int t    = threadIdx.x;
    const int lane = t & 63;
    const int w    = t >> 6;
    const int quad = lane >> 4, l15 = lane & 15;
    const int m0   = blockIdx.y << 7;
    const int n0   = blockIdx.x << 7;
    const int wm   = (w >> 1) << 6;
    const int wn   = (w & 1)  << 6;

    // staging geometry: instr j = w*2+i covers LDS [16j..16j+16) rows;
    // lane l -> row 16j + (l>>2), element chunk (l&3)*8
    const int jr0 = ((w * 2 + 0) << 4) + (lane >> 2);
    const int jr1 = ((w * 2 + 1) << 4) + (lane >> 2);
    const int kch = (lane & 3) << 3;

    bf16* lA0 = As + (w * 2 + 0) * 512;
    bf16* lA1 = As + (w * 2 + 1) * 512;
    bf16* lB0 = Bs + (w * 2 + 0) * 512;
    bf16* lB1 = Bs + (w * 2 + 1) * 512;

    f32x4 acc[4][4] = {};

    const bf16* Aseg[3] = {A0, A1, A2};
    const bf16* Bseg[3] = {B0, B1, B2};

    for (int seg = 0; seg < nseg; ++seg) {
        const bf16* Ap0 = Aseg[seg] + (size_t)(m0 + jr0) * DD + kch;
        const bf16* Ap1 = Aseg[seg] + (size_t)(m0 + jr1) * DD + kch;
        const bf16* Bp0 = Bseg[seg] + (size_t)(n0 + jr0) * DD + kch;
        const bf16* Bp1 = Bseg[seg] + (size_t)(n0 + jr1) * DD + kch;
        for (int k0 = 0; k0 < DD; k0 += 32) {
            __syncthreads();           // previous tile fully consumed
            gld16(Ap0 + k0, lA0);
            gld16(Ap1 + k0, lA1);
            gld16(Bp0 + k0, lB0);
            gld16(Bp1 + k0, lB1);
            __syncthreads();           // drains vmcnt: DMA complete
            bf16x8 af[4], bfm[4];
            #pragma unroll
            for (int mt = 0; mt < 4; ++mt)
                af[mt] = *(const bf16x8*)(As + (wm + (mt << 4) + l15) * 32 + (quad << 3));
            #pragma unroll
            for (int nt = 0; nt < 4; ++nt)
                bfm[nt] = *(const bf16x8*)(Bs + (wn + (nt << 4) + l15) * 32 + (quad << 3));
            #pragma unroll
            for (int mt = 0; mt < 4; ++mt)
                #pragma unroll
                for (int nt = 0; nt < 4; ++nt)
                    acc[mt][nt] = __builtin_amdgcn_mfma_f32_16x16x32_bf16(
                        af[mt], bfm[nt], acc[mt][nt], 0, 0, 0);
        }
    }

    if (mode == 0) {
        #pragma unroll
        for (int nt = 0; nt < 4; ++nt) {
            const int col = n0 + wn + (nt << 4) + l15;
            const int isQ = (col < 1024);
            const int nh  = col & 1023;
            const int n   = nh >> 6, h = nh & 63;
            const float bcol = isQ ? bias1[nh] : bias2[nh];
            float s = 1.f;
            if (isQ) {
                float x  = pds[h];
                float sp = fmaxf(x, 0.f) + log1pf(expf(-fabsf(x)));  // softplus
                s = (LOG2E_F * LOG2E_F / 8.0f) * sp;  // extra LOG2E: exp2 domain
            }
            bf16* dH = isQ ? oQh : oKh;
            bf16* dL = isQ ? oQl : oKl;
            #pragma unroll
            for (int mt = 0; mt < 4; ++mt) {
                #pragma unroll
                for (int reg = 0; reg < 4; ++reg) {
                    const int row = m0 + wm + (mt << 4) + (quad << 2) + reg;
                    const int bi  = row >> 11;
                    const int tt  = row & (TT - 1);
                    float val = (acc[mt][nt][reg] + bcol) * s;
                    const size_t idx = (((size_t)bi * NHD + n) * TT + tt) * HD + h;
                    bf16 hi = (bf16)val;
                    dH[idx] = hi;
                    dL[idx] = (bf16)(val - (float)hi);
                }
            }
        }
    } else if (mode == 1) {
        #pragma unroll
        for (int nt = 0; nt < 4; ++nt) {
            const int col = n0 + wn + (nt << 4) + l15;   // bt
            const int bi  = col >> 11;
            const int tt  = col & (TT - 1);
            #pragma unroll
            for (int mt = 0; mt < 4; ++mt) {
                #pragma unroll
                for (int reg = 0; reg < 4; ++reg) {
                    const int row = m0 + wm + (mt << 4) + (quad << 2) + reg;  // nh
                    float val = acc[mt][nt][reg] + bias1[row];
                    oVt[((size_t)bi * 1024 + row) * TT + tt] = (bf16)val;
                }
            }
        }
    } else {
        #pragma unroll
        for (int nt = 0; nt < 4; ++nt) {
            const int col = n0 + wn + (nt << 4) + l15;
            const float bcol = bias2[col];
            #pragma unroll
            for (int mt = 0; mt < 4; ++mt) {
                #pragma unroll
                for (int reg = 0; reg < 4; ++reg) {
                    const int row = m0 + wm + (mt << 4) + (quad << 2) + reg;
                    oF[(size_t)row * DD + col] = acc[mt][nt][reg] + bcol;
                }
            }
        }
    }
}

// ---------------------------------------------------------------------------
// MFMA flash attention, split-bf16 Q/K scores. Q frags direct from global
// (registers), K hi/lo + Vt staged in LDS. 4 blocks/CU (37.6 KB LDS).
// Vt input layout [b][n][h][t]. exp2-domain softmax (LOG2E^2 baked into Q).
// ---------------------------------------------------------------------------
__global__ __launch_bounds__(256)
void attn_mfma(const bf16* __restrict__ Qh, const bf16* __restrict__ Ql,
               const bf16* __restrict__ Kh, const bf16* __restrict__ Kl,
               const bf16* __restrict__ Vt, const unsigned* __restrict__ mbits,
               bf16* __restrict__ AO)
{
    __shared__ bf16 Ksh[64][72];
    __shared__ bf16 Ksl[64][72];
    __shared__ bf16 Vts[64][72];       // [h][s]
    __shared__ bf16 Ps[4][16][72];     // per-wave P tile [q][s]
    __shared__ unsigned msk[64][2];

    const int t    = threadIdx.x;
    const int lane = t & 63;
    const int w    = t >> 6;
    const int quad = lane >> 4, l15 = lane & 15;
    const int bn   = blockIdx.y;
    const int b    = bn >> 4, n = bn & 15;
    const int q0   = blockIdx.x << 6;

    const bf16* Qbh = Qh + (size_t)bn * TT * HD;
    const bf16* Qbl = Ql + (size_t)bn * TT * HD;
    const bf16* Kbh = Kh + (size_t)bn * TT * HD;
    const bf16* Kbl = Kl + (size_t)bn * TT * HD;
    const bf16* Vtb = Vt + (size_t)bn * HD * TT;

    // Q fragments: registers only (each wave touches only its 16 q-rows)
    const int qrow = q0 + (w << 4) + l15;
    bf16x8 qfh[2], qfl[2];
    qfh[0] = *(const bf16x8*)(Qbh + (size_t)qrow * HD + (quad << 3));
    qfh[1] = *(const bf16x8*)(Qbh + (size_t)qrow * HD + 32 + (quad << 3));
    qfl[0] = *(const bf16x8*)(Qbl + (size_t)qrow * HD + (quad << 3));
    qfl[1] = *(const bf16x8*)(Qbl + (size_t)qrow * HD + 32 + (quad << 3));

    f32x4 O[4];
    #pragma unroll
    for (int i = 0; i < 4; ++i) O[i] = (f32x4){0.f,0.f,0.f,0.f};
    float m_i[4] = {-INFINITY, -INFINITY, -INFINITY, -INFINITY};
    float l_i[4] = {0.f, 0.f, 0.f, 0.f};

    const int rS = t >> 2, cS = (t & 3) << 4;   // staging map (rows x 32B)

    for (int kb = 0; kb < TT; kb += 64) {
        // prefetch globals into regs
        const bf16* kph = Kbh + (size_t)(kb + rS) * HD + cS;
        const bf16* kpl = Kbl + (size_t)(kb + rS) * HD + cS;
        bf16x8 kh0 = *(const bf16x8*)kph;
        bf16x8 kh1 = *(const bf16x8*)(kph + 8);
        bf16x8 kl0 = *(const bf16x8*)kpl;
        bf16x8 kl1 = *(const bf16x8*)(kpl + 8);
        const bf16* vp = Vtb + (size_t)rS * TT + kb + cS;   // row h=rS, cols s
        bf16x8 v0v = *(const bf16x8*)vp;
        bf16x8 v1v = *(const bf16x8*)(vp + 8);
        unsigned mw = 0;
        if (t < 128)
            mw = mbits[((size_t)b * TT + q0 + (t >> 1)) * (TT / 32) + (kb >> 5) + (t & 1)];

        __syncthreads();   // previous tile fully consumed
        *(bf16x8*)&Ksh[rS][cS]     = kh0;
        *(bf16x8*)&Ksh[rS][cS + 8] = kh1;
        *(bf16x8*)&Ksl[rS][cS]     = kl0;
        *(bf16x8*)&Ksl[rS][cS + 8] = kl1;
        *(bf16x8*)&Vts[rS][cS]     = v0v;
        *(bf16x8*)&Vts[rS][cS + 8] = v1v;
        if (t < 128) msk[t >> 1][t & 1] = mw;
        __syncthreads();

        // S = Q K^T, split: Qh*Kh + Qh*Kl + Ql*Kh
        f32x4 s_acc[4];
        #pragma unroll
        for (int i = 0; i < 4; ++i) s_acc[i] = (f32x4){0.f,0.f,0.f,0.f};
        #pragma unroll
        for (int k2 = 0; k2 < 2; ++k2) {
            #pragma unroll
            for (int nt = 0; nt < 4; ++nt) {
                bf16x8 bkh = *(const bf16x8*)&Ksh[(nt << 4) + l15][(k2 << 5) + (quad << 3)];
                bf16x8 bkl = *(const bf16x8*)&Ksl[(nt << 4) + l15][(k2 << 5) + (quad << 3)];
                s_acc[nt] = __builtin_amdgcn_mfma_f32_16x16x32_bf16(qfh[k2], bkh, s_acc[nt], 0, 0, 0);
                s_acc[nt] = __builtin_amdgcn_mfma_f32_16x16x32_bf16(qfh[k2], bkl, s_acc[nt], 0, 0, 0);
                s_acc[nt] = __builtin_amdgcn_mfma_f32_16x16x32_bf16(qfl[k2], bkh, s_acc[nt], 0, 0, 0);
            }
        }

        // mask + online softmax (exp2 domain); write P (bf16) to per-wave LDS
        #pragma unroll
        for (int reg = 0; reg < 4; ++reg) {
            const int rowb = (w << 4) + (quad << 2) + reg;
            const unsigned w0 = msk[rowb][0], w1 = msk[rowb][1];
            float sv[4];
            #pragma unroll
            for (int nt = 0; nt < 4; ++nt) {
                const unsigned word = (nt < 2) ? w0 : w1;
                const int bit = ((nt & 1) << 4) + l15;
                sv[nt] = ((word >> bit) & 1u) ? s_acc[nt][reg] : NEGINF_F;
            }
            float mx = fmaxf(fmaxf(sv[0], sv[1]), fmaxf(sv[2], sv[3]));
            mx = fmaxf(mx, __shfl_xor(mx, 1));
            mx = fmaxf(mx, __shfl_xor(mx, 2));
            mx = fmaxf(mx, __shfl_xor(mx, 4));
            mx = fmaxf(mx, __shfl_xor(mx, 8));
            const float mnew  = fmaxf(m_i[reg], mx);
            const float alpha = exp2f(m_i[reg] - mnew);   // exp2(-inf)=0 first tile
            float p[4], sum = 0.f;
            #pragma unroll
            for (int nt = 0; nt < 4; ++nt) { p[nt] = exp2f(sv[nt] - mnew); sum += p[nt]; }
            sum += __shfl_xor(sum, 1);
            sum += __shfl_xor(sum, 2);
            sum += __shfl_xor(sum, 4);
            sum += __shfl_xor(sum, 8);
            l_i[reg] = l_i[reg] * alpha + sum;
            m_i[reg] = mnew;
            #pragma unroll
            for (int nt = 0; nt < 4; ++nt) {
                O[nt][reg] *= alpha;
                Ps[w][(quad << 2) + reg][(nt << 4) + l15] = (bf16)p[nt];
            }
        }

        // O += P V
        #pragma unroll
        for (int s2 = 0; s2 < 2; ++s2) {
            bf16x8 ap = *(const bf16x8*)&Ps[w][l15][(s2 << 5) + (quad << 3)];
            #pragma unroll
            for (int nt = 0; nt < 4; ++nt) {
                bf16x8 bv = *(const bf16x8*)&Vts[(nt << 4) + l15][(s2 << 5) + (quad << 3)];
                O[nt] = __builtin_amdgcn_mfma_f32_16x16x32_bf16(ap, bv, O[nt], 0, 0, 0);
            }
        }
    }

    // normalize + write AO (bf16, [B*T][N*H])
    #pragma unroll
    for (int reg = 0; reg < 4; ++reg) {
        const float inv = 1.0f / l_i[reg];
        const int q = q0 + (w << 4) + (quad << 2) + reg;
        const size_t base = ((size_t)b * TT + q) * (NHD * HD) + (size_t)n * HD;
        #pragma unroll
        for (int nt = 0; nt < 4; ++nt)
            AO[base + (nt << 4) + l15] = (bf16)(O[nt][reg] * inv);
    }
}

// ---------------------------------------------------------------------------
extern "C" void kernel_launch(void* const* d_in, const int* in_sizes, int n_in,
                              void* d_out, int out_size, void* d_ws, size_t ws_size,
                              hipStream_t stream)
{
    const float* X   = (const float*)d_in[0];
    const int*   msk = (const int*)d_in[1];
    const float* wq  = (const float*)d_in[2];
    const float* bq  = (const float*)d_in[3];
    const float* wk  = (const float*)d_in[4];
    const float* bk  = (const float*)d_in[5];
    const float* wv  = (const float*)d_in[6];
    const float* bv  = (const float*)d_in[7];
    const float* wo  = (const float*)d_in[8];
    const float* bo  = (const float*)d_in[9];
    const float* pds = (const float*)d_in[10];
    float* out = (float*)d_out;

    bf16* ws   = (bf16*)d_ws;
    bf16* Xh   = ws;                      // 4M  (later aliased by AO)
    bf16* Xl   = ws + 4194304;            // 4M  (later aliased by Vt)
    bf16* WQKh = ws + 8388608;            // 2M  [2048 nh'][1024 d]
    bf16* WQKl = ws + 10485760;           // 2M
    bf16* Wvh  = ws + 12582912;           // 1M  [nh][d]
    bf16* Wob  = ws + 13631488;           // 1M  [d][nh]
    bf16* Qhb  = ws + 14680064;           // 4M  [b][n][t][h]
    bf16* Qlb  = ws + 18874368;
    bf16* Khb  = ws + 23068672;
    bf16* Klb  = ws + 27262976;
    unsigned* mbits = (unsigned*)(ws + 31457280);   // 1 MB
    bf16* Vtb  = Xl;                      // alias: Xl dead after QK-GEMM
    bf16* AOb  = Xh;                      // alias: Xh dead after V-GEMM

    dim3 blk(256);

    split_x<<<4096, blk, 0, stream>>>(X, Xh, Xl, MM * DD / 4);
    cvt_transpose_split<<<dim3(32, 32), blk, 0, stream>>>(wq, WQKh, WQKl, 1);
    cvt_transpose_split<<<dim3(32, 32), blk, 0, stream>>>(wk, WQKh + 1048576, WQKl + 1048576, 1);
    cvt_transpose_split<<<dim3(32, 32), blk, 0, stream>>>(wv, Wvh, Wvh, 0);
    cvt_bf16<<<1024, blk, 0, stream>>>(wo, Wob, DD * NHD * HD / 4);
    pack_mask<<<32768, blk, 0, stream>>>(msk, mbits, BB * TT * TT);

    // QK projection: M=4096, N=2048, K=3072 virtual (Xh*Wh + Xh*Wl + Xl*Wh)
    gemm128<<<dim3(16, 32), blk, 0, stream>>>(
        Xh, Xh, Xl, WQKh, WQKl, WQKh, 3, bq, bk, pds,
        Qhb, Qlb, Khb, Klb, nullptr, nullptr, 0);

    // V projection, transposed output: M=1024 (nh), N=4096 (bt), K=1024
    gemm128<<<dim3(32, 8), blk, 0, stream>>>(
        Wvh, nullptr, nullptr, Xh, nullptr, nullptr, 1, bv, nullptr, nullptr,
        nullptr, nullptr, nullptr, nullptr, Vtb, nullptr, 1);

    dim3 ga(TT / 64, BB * NHD);   // (32, 32)
    attn_mfma<<<ga, blk, 0, stream>>>(Qhb, Qlb, Khb, Klb, Vtb, mbits, AOb);

    // output projection: M=4096, N=1024, K=1024, fp32 out
    gemm128<<<dim3(8, 32), blk, 0, stream>>>(
        AOb, nullptr, nullptr, Wob, nullptr, nullptr, 1, nullptr, bo, nullptr,
        nullptr, nullptr, nullptr, nullptr, nullptr, out, 2);
}

// Round 6
// 366.651 us; speedup vs baseline: 3.1764x; 1.1031x over previous
//
#include <hip/hip_runtime.h>
#include <math.h>

typedef __bf16 bf16;
typedef __attribute__((ext_vector_type(8))) __bf16 bf16x8;
typedef __attribute__((ext_vector_type(4))) __bf16 bf16x4;
typedef __attribute__((ext_vector_type(4))) float f32x4;

#define BB 2
#define TT 2048
#define DD 1024
#define NHD 16
#define HD 64
#define MM (BB*TT)          // 4096
#define LOG2E_F 1.442695041f
#define NEGINF_F (-1.0e9f)

// async global->LDS, 16B per lane; LDS dest must be wave-uniform base
__device__ __forceinline__ void gld16(const bf16* g, bf16* l)
{
    __builtin_amdgcn_global_load_lds(
        (const __attribute__((address_space(1))) unsigned int*)g,
        (__attribute__((address_space(3))) unsigned int*)l, 16, 0, 0);
}

// ---------------------------------------------------------------------------
// fp32 -> bf16 hi/lo split (elementwise)
// ---------------------------------------------------------------------------
__global__ __launch_bounds__(256)
void split_x(const float* __restrict__ in, bf16* __restrict__ hi,
             bf16* __restrict__ lo, int n4)
{
    int i = blockIdx.x * 256 + threadIdx.x;
    if (i < n4) {
        float4 v = ((const float4*)in)[i];
        float f[4] = {v.x, v.y, v.z, v.w};
        bf16x4 h, l;
        #pragma unroll
        for (int j = 0; j < 4; ++j) {
            bf16 hh = (bf16)f[j];
            h[j] = hh;
            l[j] = (bf16)(f[j] - (float)hh);
        }
        *(bf16x4*)(hi + (size_t)i * 4) = h;
        *(bf16x4*)(lo + (size_t)i * 4) = l;
    }
}

// ---------------------------------------------------------------------------
// fused weight prep: z=0 wq->transpose-split, z=1 wk->transpose-split,
// z=2 wv->transpose (hi only), z=3 wo->plain bf16 convert
// ---------------------------------------------------------------------------
__global__ __launch_bounds__(256)
void prep_weights(const float* __restrict__ wq, const float* __restrict__ wk,
                  const float* __restrict__ wv, const float* __restrict__ wo,
                  bf16* __restrict__ qkh, bf16* __restrict__ qkl,
                  bf16* __restrict__ vh, bf16* __restrict__ ob)
{
    __shared__ float tile[32][33];
    const int z  = blockIdx.z;
    const int t  = threadIdx.x;
    const int r  = t >> 3;
    const int c4 = (t & 7) << 2;
    const int bx = blockIdx.x << 5;   // nh block
    const int by = blockIdx.y << 5;   // d block
    if (z == 3) {
        float4 v = *(const float4*)(wo + (size_t)(by + r) * 1024 + bx + c4);
        bf16x4 o = { (bf16)v.x, (bf16)v.y, (bf16)v.z, (bf16)v.w };
        *(bf16x4*)(ob + (size_t)(by + r) * 1024 + bx + c4) = o;
        return;
    }
    const float* src = (z == 0) ? wq : ((z == 1) ? wk : wv);
    bf16* oh = (z == 0) ? qkh : ((z == 1) ? qkh + 1048576 : vh);
    bf16* ol = (z == 0) ? qkl : ((z == 1) ? qkl + 1048576 : nullptr);

    float4 v = *(const float4*)(src + (size_t)(by + r) * 1024 + bx + c4);
    tile[r][c4+0] = v.x; tile[r][c4+1] = v.y; tile[r][c4+2] = v.z; tile[r][c4+3] = v.w;
    __syncthreads();
    bf16x4 hv, lv;
    #pragma unroll
    for (int j = 0; j < 4; ++j) {
        float f = tile[c4 + j][r];
        bf16 h = (bf16)f;
        hv[j] = h;
        lv[j] = (bf16)(f - (float)h);
    }
    *(bf16x4*)(oh + (size_t)(bx + r) * 1024 + by + c4) = hv;
    if (ol)
        *(bf16x4*)(ol + (size_t)(bx + r) * 1024 + by + c4) = lv;
}

// ---------------------------------------------------------------------------
// int32 mask -> bitmask via 64-lane ballot
// ---------------------------------------------------------------------------
__global__ __launch_bounds__(256)
void pack_mask(const int* __restrict__ m, unsigned* __restrict__ bits, int n)
{
    int i = blockIdx.x * 256 + threadIdx.x;
    int lane = threadIdx.x & 63;
    int v = (i < n) ? m[i] : 0;
    unsigned long long b = __ballot(v != 0);
    if ((lane & 31) == 0 && i < n)
        bits[i >> 5] = (unsigned)(b >> (lane & 32));
}

// ---------------------------------------------------------------------------
// m97-style 128x128 MFMA GEMM, BK=32, global_load_lds staging, segmented K.
// C[m][n] = sum_seg sum_k Aseg[m][k] * Bseg[n][k]   (all operands [rows][1024])
// mode 0: QK-proj epilogue — col<1024: Q (scale, split hi/lo to [b,n,t,h]);
//         col>=1024: K (split hi/lo).  Q scale = (LOG2E^2/8)*softplus.
// mode 1: Vt epilogue — rows=nh, cols=bt; out[b*1024+row][t] bf16; bias1[row].
// mode 2: plain fp32 out[row*1024+col] + bias2[col].
// ---------------------------------------------------------------------------
__global__ __launch_bounds__(256)
void gemm128(const bf16* __restrict__ A0, const bf16* __restrict__ A1,
             const bf16* __restrict__ A2, const bf16* __restrict__ B0,
             const bf16* __restrict__ B1, const bf16* __restrict__ B2,
             const int nseg,
             const float* __restrict__ bias1, const float* __restrict__ bias2,
             const float* __restrict__ pds,
             bf16* __restrict__ oQh, bf16* __restrict__ oQl,
             bf16* __restrict__ oKh, bf16* __restrict__ oKl,
             bf16* __restrict__ oVt, float* __restrict__ oF,
             const int mode)
{
    __shared__ bf16 As[128 * 32];
    __shared__ bf16 Bs[128 * 32];

    const int t    = threadIdx.x;
    const int lane = t & 63;
    const int w    = t >> 6;
    const int quad = lane >> 4, l15 = lane & 15;
    const int m0   = blockIdx.y << 7;
    const int n0   = blockIdx.x << 7;
    const int wm   = (w >> 1) << 6;
    const int wn   = (w & 1)  << 6;

    const int jr0 = ((w * 2 + 0) << 4) + (lane >> 2);
    const int jr1 = ((w * 2 + 1) << 4) + (lane >> 2);
    const int kch = (lane & 3) << 3;

    bf16* lA0 = As + (w * 2 + 0) * 512;
    bf16* lA1 = As + (w * 2 + 1) * 512;
    bf16* lB0 = Bs + (w * 2 + 0) * 512;
    bf16* lB1 = Bs + (w * 2 + 1) * 512;

    f32x4 acc[4][4] = {};

    const bf16* Aseg[3] = {A0, A1, A2};
    const bf16* Bseg[3] = {B0, B1, B2};

    for (int seg = 0; seg < nseg; ++seg) {
        const bf16* Ap0 = Aseg[seg] + (size_t)(m0 + jr0) * DD + kch;
        const bf16* Ap1 = Aseg[seg] + (size_t)(m0 + jr1) * DD + kch;
        const bf16* Bp0 = Bseg[seg] + (size_t)(n0 + jr0) * DD + kch;
        const bf16* Bp1 = Bseg[seg] + (size_t)(n0 + jr1) * DD + kch;
        for (int k0 = 0; k0 < DD; k0 += 32) {
            __syncthreads();
            gld16(Ap0 + k0, lA0);
            gld16(Ap1 + k0, lA1);
            gld16(Bp0 + k0, lB0);
            gld16(Bp1 + k0, lB1);
            __syncthreads();
            bf16x8 af[4], bfm[4];
            #pragma unroll
            for (int mt = 0; mt < 4; ++mt)
                af[mt] = *(const bf16x8*)(As + (wm + (mt << 4) + l15) * 32 + (quad << 3));
            #pragma unroll
            for (int nt = 0; nt < 4; ++nt)
                bfm[nt] = *(const bf16x8*)(Bs + (wn + (nt << 4) + l15) * 32 + (quad << 3));
            #pragma unroll
            for (int mt = 0; mt < 4; ++mt)
                #pragma unroll
                for (int nt = 0; nt < 4; ++nt)
                    acc[mt][nt] = __builtin_amdgcn_mfma_f32_16x16x32_bf16(
                        af[mt], bfm[nt], acc[mt][nt], 0, 0, 0);
        }
    }

    if (mode == 0) {
        #pragma unroll
        for (int nt = 0; nt < 4; ++nt) {
            const int col = n0 + wn + (nt << 4) + l15;
            const int isQ = (col < 1024);
            const int nh  = col & 1023;
            const int n   = nh >> 6, h = nh & 63;
            const float bcol = isQ ? bias1[nh] : bias2[nh];
            float s = 1.f;
            if (isQ) {
                float x  = pds[h];
                float sp = fmaxf(x, 0.f) + log1pf(expf(-fabsf(x)));  // softplus
                s = (LOG2E_F * LOG2E_F / 8.0f) * sp;  // extra LOG2E: exp2 domain
            }
            bf16* dH = isQ ? oQh : oKh;
            bf16* dL = isQ ? oQl : oKl;
            #pragma unroll
            for (int mt = 0; mt < 4; ++mt) {
                #pragma unroll
                for (int reg = 0; reg < 4; ++reg) {
                    const int row = m0 + wm + (mt << 4) + (quad << 2) + reg;
                    const int bi  = row >> 11;
                    const int tt  = row & (TT - 1);
                    float val = (acc[mt][nt][reg] + bcol) * s;
                    const size_t idx = (((size_t)bi * NHD + n) * TT + tt) * HD + h;
                    bf16 hi = (bf16)val;
                    dH[idx] = hi;
                    dL[idx] = (bf16)(val - (float)hi);
                }
            }
        }
    } else if (mode == 1) {
        #pragma unroll
        for (int nt = 0; nt < 4; ++nt) {
            const int col = n0 + wn + (nt << 4) + l15;   // bt
            const int bi  = col >> 11;
            const int tt  = col & (TT - 1);
            #pragma unroll
            for (int mt = 0; mt < 4; ++mt) {
                #pragma unroll
                for (int reg = 0; reg < 4; ++reg) {
                    const int row = m0 + wm + (mt << 4) + (quad << 2) + reg;  // nh
                    float val = acc[mt][nt][reg] + bias1[row];
                    oVt[((size_t)bi * 1024 + row) * TT + tt] = (bf16)val;
                }
            }
        }
    } else {
        #pragma unroll
        for (int nt = 0; nt < 4; ++nt) {
            const int col = n0 + wn + (nt << 4) + l15;
            const float bcol = bias2[col];
            #pragma unroll
            for (int mt = 0; mt < 4; ++mt) {
                #pragma unroll
                for (int reg = 0; reg < 4; ++reg) {
                    const int row = m0 + wm + (mt << 4) + (quad << 2) + reg;
                    oF[(size_t)row * DD + col] = acc[mt][nt][reg] + bcol;
                }
            }
        }
    }
}

// ---------------------------------------------------------------------------
// MFMA flash attention, TRANSPOSED-score formulation:
//   S^T = K·Q^T  (C: row=s, col=q=l15)  -> softmax reduction over s is
//   15 in-lane ops + 2 shuffles (xor16, xor32); m/l state = 1 scalar/lane.
//   O^T = Vt·P^T (C: row=h, col=q=l15).
// Split-bf16 Q/K scores; Q frags in registers; K hi/lo + Vt in LDS.
// ---------------------------------------------------------------------------
__global__ __launch_bounds__(256)
void attn_mfma(const bf16* __restrict__ Qh, const bf16* __restrict__ Ql,
               const bf16* __restrict__ Kh, const bf16* __restrict__ Kl,
               const bf16* __restrict__ Vt, const unsigned* __restrict__ mbits,
               bf16* __restrict__ AO)
{
    __shared__ bf16 Ksh[64][72];
    __shared__ bf16 Ksl[64][72];
    __shared__ bf16 Vts[64][72];       // [h][s]
    __shared__ bf16 Ps[4][16][72];     // per-wave P^T-as-[q][s]
    __shared__ unsigned msk[64][2];

    const int t    = threadIdx.x;
    const int lane = t & 63;
    const int w    = t >> 6;
    const int quad = lane >> 4, l15 = lane & 15;
    const int bn   = blockIdx.y;
    const int b    = bn >> 4, n = bn & 15;
    const int q0   = blockIdx.x << 6;

    const bf16* Qbh = Qh + (size_t)bn * TT * HD;
    const bf16* Qbl = Ql + (size_t)bn * TT * HD;
    const bf16* Kbh = Kh + (size_t)bn * TT * HD;
    const bf16* Kbl = Kl + (size_t)bn * TT * HD;
    const bf16* Vtb = Vt + (size_t)bn * HD * TT;

    // Q fragments (B-operand: n=q=l15, k=h) — registers, loaded once
    const int qrow = q0 + (w << 4) + l15;
    bf16x8 qfh[2], qfl[2];
    qfh[0] = *(const bf16x8*)(Qbh + (size_t)qrow * HD + (quad << 3));
    qfh[1] = *(const bf16x8*)(Qbh + (size_t)qrow * HD + 32 + (quad << 3));
    qfl[0] = *(const bf16x8*)(Qbl + (size_t)qrow * HD + (quad << 3));
    qfl[1] = *(const bf16x8*)(Qbl + (size_t)qrow * HD + 32 + (quad << 3));

    f32x4 O[4];                         // O^T: row h=nt*16+quad*4+reg, col q=l15
    #pragma unroll
    for (int i = 0; i < 4; ++i) O[i] = (f32x4){0.f,0.f,0.f,0.f};
    float m_i = -INFINITY;              // per-lane: state for q = qrow
    float l_i = 0.f;

    const int rS = t >> 2, cS = (t & 3) << 4;   // staging map (rows x 32B)

    for (int kb = 0; kb < TT; kb += 64) {
        // prefetch globals into regs
        const bf16* kph = Kbh + (size_t)(kb + rS) * HD + cS;
        const bf16* kpl = Kbl + (size_t)(kb + rS) * HD + cS;
        bf16x8 kh0 = *(const bf16x8*)kph;
        bf16x8 kh1 = *(const bf16x8*)(kph + 8);
        bf16x8 kl0 = *(const bf16x8*)kpl;
        bf16x8 kl1 = *(const bf16x8*)(kpl + 8);
        const bf16* vp = Vtb + (size_t)rS * TT + kb + cS;   // row h=rS, cols s
        bf16x8 v0v = *(const bf16x8*)vp;
        bf16x8 v1v = *(const bf16x8*)(vp + 8);
        unsigned mw = 0;
        if (t < 128)
            mw = mbits[((size_t)b * TT + q0 + (t >> 1)) * (TT / 32) + (kb >> 5) + (t & 1)];

        __syncthreads();   // previous tile fully consumed
        *(bf16x8*)&Ksh[rS][cS]     = kh0;
        *(bf16x8*)&Ksh[rS][cS + 8] = kh1;
        *(bf16x8*)&Ksl[rS][cS]     = kl0;
        *(bf16x8*)&Ksl[rS][cS + 8] = kl1;
        *(bf16x8*)&Vts[rS][cS]     = v0v;
        *(bf16x8*)&Vts[rS][cS + 8] = v1v;
        if (t < 128) msk[t >> 1][t & 1] = mw;
        __syncthreads();

        // S^T = K Q^T (rows s, cols q), split: Kh*Qh + Kl*Qh + Kh*Ql
        f32x4 s_acc[4];
        #pragma unroll
        for (int i = 0; i < 4; ++i) s_acc[i] = (f32x4){0.f,0.f,0.f,0.f};
        #pragma unroll
        for (int k2 = 0; k2 < 2; ++k2) {
            #pragma unroll
            for (int nt = 0; nt < 4; ++nt) {
                bf16x8 bkh = *(const bf16x8*)&Ksh[(nt << 4) + l15][(k2 << 5) + (quad << 3)];
                bf16x8 bkl = *(const bf16x8*)&Ksl[(nt << 4) + l15][(k2 << 5) + (quad << 3)];
                s_acc[nt] = __builtin_amdgcn_mfma_f32_16x16x32_bf16(bkh, qfh[k2], s_acc[nt], 0, 0, 0);
                s_acc[nt] = __builtin_amdgcn_mfma_f32_16x16x32_bf16(bkl, qfh[k2], s_acc[nt], 0, 0, 0);
                s_acc[nt] = __builtin_amdgcn_mfma_f32_16x16x32_bf16(bkh, qfl[k2], s_acc[nt], 0, 0, 0);
            }
        }

        // per-lane softmax over s (16 local vals + cross-quad shuffles)
        const unsigned w0 = msk[(w << 4) + l15][0];
        const unsigned w1 = msk[(w << 4) + l15][1];
        float sv[16];
        #pragma unroll
        for (int nt = 0; nt < 4; ++nt) {
            const unsigned word = (nt & 2) ? w1 : w0;
            #pragma unroll
            for (int reg = 0; reg < 4; ++reg) {
                const int bit = ((nt & 1) << 4) + (quad << 2) + reg;
                sv[nt * 4 + reg] = ((word >> bit) & 1u) ? s_acc[nt][reg] : NEGINF_F;
            }
        }
        float mx = sv[0];
        #pragma unroll
        for (int i = 1; i < 16; ++i) mx = fmaxf(mx, sv[i]);
        mx = fmaxf(mx, __shfl_xor(mx, 16));
        mx = fmaxf(mx, __shfl_xor(mx, 32));
        const float mnew  = fmaxf(m_i, mx);
        const float alpha = exp2f(m_i - mnew);   // exp2(-inf)=0 first tile
        float p[16], sum = 0.f;
        #pragma unroll
        for (int i = 0; i < 16; ++i) { p[i] = exp2f(sv[i] - mnew); sum += p[i]; }
        sum += __shfl_xor(sum, 16);
        sum += __shfl_xor(sum, 32);
        l_i = l_i * alpha + sum;
        m_i = mnew;
        #pragma unroll
        for (int nt = 0; nt < 4; ++nt) {
            O[nt][0] *= alpha; O[nt][1] *= alpha;
            O[nt][2] *= alpha; O[nt][3] *= alpha;
            #pragma unroll
            for (int reg = 0; reg < 4; ++reg)
                Ps[w][l15][(nt << 4) + (quad << 2) + reg] = (bf16)p[nt * 4 + reg];
        }

        // O^T += Vt P^T  (A=Vt rows h, B=P rows q)
        #pragma unroll
        for (int s2 = 0; s2 < 2; ++s2) {
            bf16x8 ap = *(const bf16x8*)&Ps[w][l15][(s2 << 5) + (quad << 3)];
            #pragma unroll
            for (int nt = 0; nt < 4; ++nt) {
                bf16x8 bv = *(const bf16x8*)&Vts[(nt << 4) + l15][(s2 << 5) + (quad << 3)];
                O[nt] = __builtin_amdgcn_mfma_f32_16x16x32_bf16(bv, ap, O[nt], 0, 0, 0);
            }
        }
    }

    // normalize + write AO (bf16, [B*T][N*H]); lane owns col q, rows h
    {
        const float inv = 1.0f / l_i;
        const size_t base = ((size_t)b * TT + qrow) * (NHD * HD) + (size_t)n * HD;
        #pragma unroll
        for (int nt = 0; nt < 4; ++nt) {
            bf16x4 o = { (bf16)(O[nt][0] * inv), (bf16)(O[nt][1] * inv),
                         (bf16)(O[nt][2] * inv), (bf16)(O[nt][3] * inv) };
            *(bf16x4*)(AO + base + (nt << 4) + (quad << 2)) = o;
        }
    }
}

// ---------------------------------------------------------------------------
extern "C" void kernel_launch(void* const* d_in, const int* in_sizes, int n_in,
                              void* d_out, int out_size, void* d_ws, size_t ws_size,
                              hipStream_t stream)
{
    const float* X   = (const float*)d_in[0];
    const int*   msk = (const int*)d_in[1];
    const float* wq  = (const float*)d_in[2];
    const float* bq  = (const float*)d_in[3];
    const float* wk  = (const float*)d_in[4];
    const float* bk  = (const float*)d_in[5];
    const float* wv  = (const float*)d_in[6];
    const float* bv  = (const float*)d_in[7];
    const float* wo  = (const float*)d_in[8];
    const float* bo  = (const float*)d_in[9];
    const float* pds = (const float*)d_in[10];
    float* out = (float*)d_out;

    bf16* ws   = (bf16*)d_ws;
    bf16* Xh   = ws;                      // 4M  (later aliased by AO)
    bf16* Xl   = ws + 4194304;            // 4M  (later aliased by Vt)
    bf16* WQKh = ws + 8388608;            // 2M  [2048 nh'][1024 d]
    bf16* WQKl = ws + 10485760;           // 2M
    bf16* Wvh  = ws + 12582912;           // 1M  [nh][d]
    bf16* Wob  = ws + 13631488;           // 1M  [d][nh]
    bf16* Qhb  = ws + 14680064;           // 4M  [b][n][t][h]
    bf16* Qlb  = ws + 18874368;
    bf16* Khb  = ws + 23068672;
    bf16* Klb  = ws + 27262976;
    unsigned* mbits = (unsigned*)(ws + 31457280);   // 1 MB
    bf16* Vtb  = Xl;                      // alias: Xl dead after QK-GEMM
    bf16* AOb  = Xh;                      // alias: Xh dead after V-GEMM

    dim3 blk(256);

    split_x<<<4096, blk, 0, stream>>>(X, Xh, Xl, MM * DD / 4);
    prep_weights<<<dim3(32, 32, 4), blk, 0, stream>>>(wq, wk, wv, wo,
                                                      WQKh, WQKl, Wvh, Wob);
    pack_mask<<<32768, blk, 0, stream>>>(msk, mbits, BB * TT * TT);

    // QK projection: M=4096, N=2048, K=3072 virtual (Xh*Wh + Xh*Wl + Xl*Wh)
    gemm128<<<dim3(16, 32), blk, 0, stream>>>(
        Xh, Xh, Xl, WQKh, WQKl, WQKh, 3, bq, bk, pds,
        Qhb, Qlb, Khb, Klb, nullptr, nullptr, 0);

    // V projection, transposed output: M=1024 (nh), N=4096 (bt), K=1024
    gemm128<<<dim3(32, 8), blk, 0, stream>>>(
        Wvh, nullptr, nullptr, Xh, nullptr, nullptr, 1, bv, nullptr, nullptr,
        nullptr, nullptr, nullptr, nullptr, Vtb, nullptr, 1);

    dim3 ga(TT / 64, BB * NHD);   // (32, 32)
    attn_mfma<<<ga, blk, 0, stream>>>(Qhb, Qlb, Khb, Klb, Vtb, mbits, AOb);

    // output projection: M=4096, N=1024, K=1024, fp32 out
    gemm128<<<dim3(8, 32), blk, 0, stream>>>(
        AOb, nullptr, nullptr, Wob, nullptr, nullptr, 1, nullptr, bo, nullptr,
        nullptr, nullptr, nullptr, nullptr, nullptr, out, 2);
}

// Round 7
// 344.453 us; speedup vs baseline: 3.3811x; 1.0644x over previous
//
#include <hip/hip_runtime.h>
#include <math.h>

typedef __bf16 bf16;
typedef __attribute__((ext_vector_type(8))) __bf16 bf16x8;
typedef __attribute__((ext_vector_type(4))) __bf16 bf16x4;
typedef __attribute__((ext_vector_type(4))) float f32x4;

#define BB 2
#define TT 2048
#define DD 1024
#define NHD 16
#define HD 64
#define MM (BB*TT)          // 4096
#define LOG2E_F 1.442695041f
#define NEGINF_F (-1.0e9f)

// async global->LDS, 16B per lane; LDS dest must be wave-uniform base
__device__ __forceinline__ void gld16(const bf16* g, bf16* l)
{
    __builtin_amdgcn_global_load_lds(
        (const __attribute__((address_space(1))) unsigned int*)g,
        (__attribute__((address_space(3))) unsigned int*)l, 16, 0, 0);
}

// ---------------------------------------------------------------------------
// fused prep: [0,4096) split_x; [4096,8192) weight transpose/convert;
// [8192,40960) mask->bitmask. One dispatch, branch is block-uniform.
// ---------------------------------------------------------------------------
__global__ __launch_bounds__(256)
void prep_all(const float* __restrict__ X, const int* __restrict__ m,
              const float* __restrict__ wq, const float* __restrict__ wk,
              const float* __restrict__ wv, const float* __restrict__ wo,
              bf16* __restrict__ Xh, bf16* __restrict__ Xl,
              bf16* __restrict__ qkh, bf16* __restrict__ qkl,
              bf16* __restrict__ vh, bf16* __restrict__ ob,
              unsigned* __restrict__ bits)
{
    __shared__ float tile[32][33];
    const int bid = blockIdx.x;
    const int t   = threadIdx.x;

    if (bid < 4096) {                         // split X -> hi/lo
        int i = bid * 256 + t;                // n4 = 1048576
        float4 v = ((const float4*)X)[i];
        float f[4] = {v.x, v.y, v.z, v.w};
        bf16x4 h, l;
        #pragma unroll
        for (int j = 0; j < 4; ++j) {
            bf16 hh = (bf16)f[j];
            h[j] = hh;
            l[j] = (bf16)(f[j] - (float)hh);
        }
        *(bf16x4*)(Xh + (size_t)i * 4) = h;
        *(bf16x4*)(Xl + (size_t)i * 4) = l;
        return;
    }
    if (bid < 8192) {                         // weights
        const int idx = bid - 4096;
        const int z   = idx >> 10;            // 0:wq 1:wk 2:wv 3:wo
        const int bx  = (idx & 31) << 5;      // nh block
        const int by  = ((idx >> 5) & 31) << 5;  // d block
        const int r   = t >> 3;
        const int c4  = (t & 7) << 2;
        if (z == 3) {
            float4 v = *(const float4*)(wo + (size_t)(by + r) * 1024 + bx + c4);
            bf16x4 o = { (bf16)v.x, (bf16)v.y, (bf16)v.z, (bf16)v.w };
            *(bf16x4*)(ob + (size_t)(by + r) * 1024 + bx + c4) = o;
            return;
        }
        const float* src = (z == 0) ? wq : ((z == 1) ? wk : wv);
        bf16* oh = (z == 0) ? qkh : ((z == 1) ? qkh + 1048576 : vh);
        bf16* ol = (z == 0) ? qkl : ((z == 1) ? qkl + 1048576 : nullptr);
        float4 v = *(const float4*)(src + (size_t)(by + r) * 1024 + bx + c4);
        tile[r][c4+0] = v.x; tile[r][c4+1] = v.y;
        tile[r][c4+2] = v.z; tile[r][c4+3] = v.w;
        __syncthreads();
        bf16x4 hv, lv;
        #pragma unroll
        for (int j = 0; j < 4; ++j) {
            float f = tile[c4 + j][r];
            bf16 h = (bf16)f;
            hv[j] = h;
            lv[j] = (bf16)(f - (float)h);
        }
        *(bf16x4*)(oh + (size_t)(bx + r) * 1024 + by + c4) = hv;
        if (ol)
            *(bf16x4*)(ol + (size_t)(bx + r) * 1024 + by + c4) = lv;
        return;
    }
    {                                         // pack mask
        int i = (bid - 8192) * 256 + t;       // n = 8388608
        int lane = t & 63;
        int v = m[i];
        unsigned long long bl = __ballot(v != 0);
        if ((lane & 31) == 0)
            bits[i >> 5] = (unsigned)(bl >> (lane & 32));
    }
}

// ---------------------------------------------------------------------------
// QK projection GEMM, single K-sweep, 4-buffer staging (Ah,Al,Bh,Bl), BK=32.
// C[m][col] = Xh*Wh + Xh*Wl + Xl*Wh ; col<1024 -> Q (scaled), else K.
// 128x128 tile, 48 MFMA per k0, global_load_lds staging.
// ---------------------------------------------------------------------------
__global__ __launch_bounds__(256)
void gemm_qk(const bf16* __restrict__ Xh, const bf16* __restrict__ Xl,
             const bf16* __restrict__ Wh, const bf16* __restrict__ Wl,
             const float* __restrict__ bq, const float* __restrict__ bk,
             const float* __restrict__ pds,
             bf16* __restrict__ oQh, bf16* __restrict__ oQl,
             bf16* __restrict__ oKh, bf16* __restrict__ oKl)
{
    __shared__ bf16 Ah[128 * 32];
    __shared__ bf16 Al[128 * 32];
    __shared__ bf16 Bh[128 * 32];
    __shared__ bf16 Bl[128 * 32];

    const int t    = threadIdx.x;
    const int lane = t & 63;
    const int w    = t >> 6;
    const int quad = lane >> 4, l15 = lane & 15;
    const int m0   = blockIdx.y << 7;
    const int n0   = blockIdx.x << 7;
    const int wm   = (w >> 1) << 6;
    const int wn   = (w & 1)  << 6;

    const int jr0 = ((w * 2 + 0) << 4) + (lane >> 2);
    const int jr1 = ((w * 2 + 1) << 4) + (lane >> 2);
    const int kch = (lane & 3) << 3;

    bf16* lAh0 = Ah + (w * 2 + 0) * 512;  bf16* lAh1 = Ah + (w * 2 + 1) * 512;
    bf16* lAl0 = Al + (w * 2 + 0) * 512;  bf16* lAl1 = Al + (w * 2 + 1) * 512;
    bf16* lBh0 = Bh + (w * 2 + 0) * 512;  bf16* lBh1 = Bh + (w * 2 + 1) * 512;
    bf16* lBl0 = Bl + (w * 2 + 0) * 512;  bf16* lBl1 = Bl + (w * 2 + 1) * 512;

    const bf16* pAh0 = Xh + (size_t)(m0 + jr0) * DD + kch;
    const bf16* pAh1 = Xh + (size_t)(m0 + jr1) * DD + kch;
    const bf16* pAl0 = Xl + (size_t)(m0 + jr0) * DD + kch;
    const bf16* pAl1 = Xl + (size_t)(m0 + jr1) * DD + kch;
    const bf16* pBh0 = Wh + (size_t)(n0 + jr0) * DD + kch;
    const bf16* pBh1 = Wh + (size_t)(n0 + jr1) * DD + kch;
    const bf16* pBl0 = Wl + (size_t)(n0 + jr0) * DD + kch;
    const bf16* pBl1 = Wl + (size_t)(n0 + jr1) * DD + kch;

    f32x4 acc[4][4] = {};

    for (int k0 = 0; k0 < DD; k0 += 32) {
        __syncthreads();
        gld16(pAh0 + k0, lAh0);  gld16(pAh1 + k0, lAh1);
        gld16(pAl0 + k0, lAl0);  gld16(pAl1 + k0, lAl1);
        gld16(pBh0 + k0, lBh0);  gld16(pBh1 + k0, lBh1);
        gld16(pBl0 + k0, lBl0);  gld16(pBl1 + k0, lBl1);
        __syncthreads();

        bf16x8 ah[4], bh[4];
        #pragma unroll
        for (int mt = 0; mt < 4; ++mt)
            ah[mt] = *(const bf16x8*)(Ah + (wm + (mt << 4) + l15) * 32 + (quad << 3));
        #pragma unroll
        for (int nt = 0; nt < 4; ++nt)
            bh[nt] = *(const bf16x8*)(Bh + (wn + (nt << 4) + l15) * 32 + (quad << 3));
        #pragma unroll
        for (int mt = 0; mt < 4; ++mt)
            #pragma unroll
            for (int nt = 0; nt < 4; ++nt)
                acc[mt][nt] = __builtin_amdgcn_mfma_f32_16x16x32_bf16(
                    ah[mt], bh[nt], acc[mt][nt], 0, 0, 0);

        bf16x8 bl[4];
        #pragma unroll
        for (int nt = 0; nt < 4; ++nt)
            bl[nt] = *(const bf16x8*)(Bl + (wn + (nt << 4) + l15) * 32 + (quad << 3));
        #pragma unroll
        for (int mt = 0; mt < 4; ++mt)
            #pragma unroll
            for (int nt = 0; nt < 4; ++nt)
                acc[mt][nt] = __builtin_amdgcn_mfma_f32_16x16x32_bf16(
                    ah[mt], bl[nt], acc[mt][nt], 0, 0, 0);

        bf16x8 al[4];
        #pragma unroll
        for (int mt = 0; mt < 4; ++mt)
            al[mt] = *(const bf16x8*)(Al + (wm + (mt << 4) + l15) * 32 + (quad << 3));
        #pragma unroll
        for (int mt = 0; mt < 4; ++mt)
            #pragma unroll
            for (int nt = 0; nt < 4; ++nt)
                acc[mt][nt] = __builtin_amdgcn_mfma_f32_16x16x32_bf16(
                    al[mt], bh[nt], acc[mt][nt], 0, 0, 0);
    }

    #pragma unroll
    for (int nt = 0; nt < 4; ++nt) {
        const int col = n0 + wn + (nt << 4) + l15;
        const int isQ = (col < 1024);
        const int nh  = col & 1023;
        const int n   = nh >> 6, h = nh & 63;
        const float bcol = isQ ? bq[nh] : bk[nh];
        float s = 1.f;
        if (isQ) {
            float x  = pds[h];
            float sp = fmaxf(x, 0.f) + log1pf(expf(-fabsf(x)));  // softplus
            s = (LOG2E_F * LOG2E_F / 8.0f) * sp;  // extra LOG2E: exp2 domain
        }
        bf16* dH = isQ ? oQh : oKh;
        bf16* dL = isQ ? oQl : oKl;
        #pragma unroll
        for (int mt = 0; mt < 4; ++mt) {
            #pragma unroll
            for (int reg = 0; reg < 4; ++reg) {
                const int row = m0 + wm + (mt << 4) + (quad << 2) + reg;
                const int bi  = row >> 11;
                const int tt  = row & (TT - 1);
                float val = (acc[mt][nt][reg] + bcol) * s;
                const size_t idx = (((size_t)bi * NHD + n) * TT + tt) * HD + h;
                bf16 hi = (bf16)val;
                dH[idx] = hi;
                dL[idx] = (bf16)(val - (float)hi);
            }
        }
    }
}

// ---------------------------------------------------------------------------
// 128x128 MFMA GEMM (single operand pair), BK=32, global_load_lds staging.
// mode 1: Vt epilogue — rows=nh, cols=bt; out[b*1024+row][t] bf16; bias[row].
// mode 2: plain fp32 out[row*1024+col] + bias[col].
// ---------------------------------------------------------------------------
__global__ __launch_bounds__(256)
void gemm128(const bf16* __restrict__ A, const bf16* __restrict__ Bt,
             const float* __restrict__ bias,
             bf16* __restrict__ oVt, float* __restrict__ oF, const int mode)
{
    __shared__ bf16 As[128 * 32];
    __shared__ bf16 Bs[128 * 32];

    const int t    = threadIdx.x;
    const int lane = t & 63;
    const int w    = t >> 6;
    const int quad = lane >> 4, l15 = lane & 15;
    const int m0   = blockIdx.y << 7;
    const int n0   = blockIdx.x << 7;
    const int wm   = (w >> 1) << 6;
    const int wn   = (w & 1)  << 6;

    const int jr0 = ((w * 2 + 0) << 4) + (lane >> 2);
    const int jr1 = ((w * 2 + 1) << 4) + (lane >> 2);
    const int kch = (lane & 3) << 3;

    bf16* lA0 = As + (w * 2 + 0) * 512;
    bf16* lA1 = As + (w * 2 + 1) * 512;
    bf16* lB0 = Bs + (w * 2 + 0) * 512;
    bf16* lB1 = Bs + (w * 2 + 1) * 512;

    const bf16* Ap0 = A  + (size_t)(m0 + jr0) * DD + kch;
    const bf16* Ap1 = A  + (size_t)(m0 + jr1) * DD + kch;
    const bf16* Bp0 = Bt + (size_t)(n0 + jr0) * DD + kch;
    const bf16* Bp1 = Bt + (size_t)(n0 + jr1) * DD + kch;

    f32x4 acc[4][4] = {};

    for (int k0 = 0; k0 < DD; k0 += 32) {
        __syncthreads();
        gld16(Ap0 + k0, lA0);
        gld16(Ap1 + k0, lA1);
        gld16(Bp0 + k0, lB0);
        gld16(Bp1 + k0, lB1);
        __syncthreads();
        bf16x8 af[4], bfm[4];
        #pragma unroll
        for (int mt = 0; mt < 4; ++mt)
            af[mt] = *(const bf16x8*)(As + (wm + (mt << 4) + l15) * 32 + (quad << 3));
        #pragma unroll
        for (int nt = 0; nt < 4; ++nt)
            bfm[nt] = *(const bf16x8*)(Bs + (wn + (nt << 4) + l15) * 32 + (quad << 3));
        #pragma unroll
        for (int mt = 0; mt < 4; ++mt)
            #pragma unroll
            for (int nt = 0; nt < 4; ++nt)
                acc[mt][nt] = __builtin_amdgcn_mfma_f32_16x16x32_bf16(
                    af[mt], bfm[nt], acc[mt][nt], 0, 0, 0);
    }

    if (mode == 1) {
        #pragma unroll
        for (int nt = 0; nt < 4; ++nt) {
            const int col = n0 + wn + (nt << 4) + l15;   // bt
            const int bi  = col >> 11;
            const int tt  = col & (TT - 1);
            #pragma unroll
            for (int mt = 0; mt < 4; ++mt) {
                #pragma unroll
                for (int reg = 0; reg < 4; ++reg) {
                    const int row = m0 + wm + (mt << 4) + (quad << 2) + reg;  // nh
                    float val = acc[mt][nt][reg] + bias[row];
                    oVt[((size_t)bi * 1024 + row) * TT + tt] = (bf16)val;
                }
            }
        }
    } else {
        #pragma unroll
        for (int nt = 0; nt < 4; ++nt) {
            const int col = n0 + wn + (nt << 4) + l15;
            const float bcol = bias[col];
            #pragma unroll
            for (int mt = 0; mt < 4; ++mt) {
                #pragma unroll
                for (int reg = 0; reg < 4; ++reg) {
                    const int row = m0 + wm + (mt << 4) + (quad << 2) + reg;
                    oF[(size_t)row * DD + col] = acc[mt][nt][reg] + bcol;
                }
            }
        }
    }
}

// ---------------------------------------------------------------------------
// MFMA flash attention, transposed-score formulation (S^T = K·Q^T).
// Split-bf16 Q/K scores; Q frags in registers; K hi/lo + Vt in LDS.
// P stored to LDS as packed bf16x4 (ds_write_b64).
// ---------------------------------------------------------------------------
__global__ __launch_bounds__(256)
void attn_mfma(const bf16* __restrict__ Qh, const bf16* __restrict__ Ql,
               const bf16* __restrict__ Kh, const bf16* __restrict__ Kl,
               const bf16* __restrict__ Vt, const unsigned* __restrict__ mbits,
               bf16* __restrict__ AO)
{
    __shared__ bf16 Ksh[64][72];
    __shared__ bf16 Ksl[64][72];
    __shared__ bf16 Vts[64][72];       // [h][s]
    __shared__ bf16 Ps[4][16][72];     // per-wave P^T-as-[q][s]
    __shared__ unsigned msk[64][2];

    const int t    = threadIdx.x;
    const int lane = t & 63;
    const int w    = t >> 6;
    const int quad = lane >> 4, l15 = lane & 15;
    const int bn   = blockIdx.y;
    const int b    = bn >> 4, n = bn & 15;
    const int q0   = blockIdx.x << 6;

    const bf16* Qbh = Qh + (size_t)bn * TT * HD;
    const bf16* Qbl = Ql + (size_t)bn * TT * HD;
    const bf16* Kbh = Kh + (size_t)bn * TT * HD;
    const bf16* Kbl = Kl + (size_t)bn * TT * HD;
    const bf16* Vtb = Vt + (size_t)bn * HD * TT;

    // Q fragments (B-operand: n=q=l15, k=h) — registers, loaded once
    const int qrow = q0 + (w << 4) + l15;
    bf16x8 qfh[2], qfl[2];
    qfh[0] = *(const bf16x8*)(Qbh + (size_t)qrow * HD + (quad << 3));
    qfh[1] = *(const bf16x8*)(Qbh + (size_t)qrow * HD + 32 + (quad << 3));
    qfl[0] = *(const bf16x8*)(Qbl + (size_t)qrow * HD + (quad << 3));
    qfl[1] = *(const bf16x8*)(Qbl + (size_t)qrow * HD + 32 + (quad << 3));

    f32x4 O[4];                         // O^T: row h=nt*16+quad*4+reg, col q=l15
    #pragma unroll
    for (int i = 0; i < 4; ++i) O[i] = (f32x4){0.f,0.f,0.f,0.f};
    float m_i = -INFINITY;
    float l_i = 0.f;

    const int rS = t >> 2, cS = (t & 3) << 4;   // staging map (rows x 32B)

    for (int kb = 0; kb < TT; kb += 64) {
        // prefetch globals into regs
        const bf16* kph = Kbh + (size_t)(kb + rS) * HD + cS;
        const bf16* kpl = Kbl + (size_t)(kb + rS) * HD + cS;
        bf16x8 kh0 = *(const bf16x8*)kph;
        bf16x8 kh1 = *(const bf16x8*)(kph + 8);
        bf16x8 kl0 = *(const bf16x8*)kpl;
        bf16x8 kl1 = *(const bf16x8*)(kpl + 8);
        const bf16* vp = Vtb + (size_t)rS * TT + kb + cS;   // row h=rS, cols s
        bf16x8 v0v = *(const bf16x8*)vp;
        bf16x8 v1v = *(const bf16x8*)(vp + 8);
        unsigned mw = 0;
        if (t < 128)
            mw = mbits[((size_t)b * TT + q0 + (t >> 1)) * (TT / 32) + (kb >> 5) + (t & 1)];

        __syncthreads();   // previous tile fully consumed
        *(bf16x8*)&Ksh[rS][cS]     = kh0;
        *(bf16x8*)&Ksh[rS][cS + 8] = kh1;
        *(bf16x8*)&Ksl[rS][cS]     = kl0;
        *(bf16x8*)&Ksl[rS][cS + 8] = kl1;
        *(bf16x8*)&Vts[rS][cS]     = v0v;
        *(bf16x8*)&Vts[rS][cS + 8] = v1v;
        if (t < 128) msk[t >> 1][t & 1] = mw;
        __syncthreads();

        // S^T = K Q^T (rows s, cols q), split: Kh*Qh + Kl*Qh + Kh*Ql
        f32x4 s_acc[4];
        #pragma unroll
        for (int i = 0; i < 4; ++i) s_acc[i] = (f32x4){0.f,0.f,0.f,0.f};
        #pragma unroll
        for (int k2 = 0; k2 < 2; ++k2) {
            #pragma unroll
            for (int nt = 0; nt < 4; ++nt) {
                bf16x8 bkh = *(const bf16x8*)&Ksh[(nt << 4) + l15][(k2 << 5) + (quad << 3)];
                bf16x8 bkl = *(const bf16x8*)&Ksl[(nt << 4) + l15][(k2 << 5) + (quad << 3)];
                s_acc[nt] = __builtin_amdgcn_mfma_f32_16x16x32_bf16(bkh, qfh[k2], s_acc[nt], 0, 0, 0);
                s_acc[nt] = __builtin_amdgcn_mfma_f32_16x16x32_bf16(bkl, qfh[k2], s_acc[nt], 0, 0, 0);
                s_acc[nt] = __builtin_amdgcn_mfma_f32_16x16x32_bf16(bkh, qfl[k2], s_acc[nt], 0, 0, 0);
            }
        }

        // per-lane softmax over s (16 local vals + cross-quad shuffles)
        const unsigned w0 = msk[(w << 4) + l15][0];
        const unsigned w1 = msk[(w << 4) + l15][1];
        float sv[16];
        #pragma unroll
        for (int nt = 0; nt < 4; ++nt) {
            const unsigned word = (nt & 2) ? w1 : w0;
            #pragma unroll
            for (int reg = 0; reg < 4; ++reg) {
                const int bit = ((nt & 1) << 4) + (quad << 2) + reg;
                sv[nt * 4 + reg] = ((word >> bit) & 1u) ? s_acc[nt][reg] : NEGINF_F;
            }
        }
        float mx = sv[0];
        #pragma unroll
        for (int i = 1; i < 16; ++i) mx = fmaxf(mx, sv[i]);
        mx = fmaxf(mx, __shfl_xor(mx, 16));
        mx = fmaxf(mx, __shfl_xor(mx, 32));
        const float mnew  = fmaxf(m_i, mx);
        const float alpha = exp2f(m_i - mnew);   // exp2(-inf)=0 first tile
        float p[16], sum = 0.f;
        #pragma unroll
        for (int i = 0; i < 16; ++i) { p[i] = exp2f(sv[i] - mnew); sum += p[i]; }
        sum += __shfl_xor(sum, 16);
        sum += __shfl_xor(sum, 32);
        l_i = l_i * alpha + sum;
        m_i = mnew;
        #pragma unroll
        for (int nt = 0; nt < 4; ++nt) {
            O[nt][0] *= alpha; O[nt][1] *= alpha;
            O[nt][2] *= alpha; O[nt][3] *= alpha;
            bf16x4 pv = { (bf16)p[nt * 4 + 0], (bf16)p[nt * 4 + 1],
                          (bf16)p[nt * 4 + 2], (bf16)p[nt * 4 + 3] };
            *(bf16x4*)&Ps[w][l15][(nt << 4) + (quad << 2)] = pv;  // ds_write_b64
        }

        // O^T += Vt P^T  (A=Vt rows h, B=P rows q)
        #pragma unroll
        for (int s2 = 0; s2 < 2; ++s2) {
            bf16x8 ap = *(const bf16x8*)&Ps[w][l15][(s2 << 5) + (quad << 3)];
            #pragma unroll
            for (int nt = 0; nt < 4; ++nt) {
                bf16x8 bv = *(const bf16x8*)&Vts[(nt << 4) + l15][(s2 << 5) + (quad << 3)];
                O[nt] = __builtin_amdgcn_mfma_f32_16x16x32_bf16(bv, ap, O[nt], 0, 0, 0);
            }
        }
    }

    // normalize + write AO (bf16, [B*T][N*H]); lane owns col q, rows h
    {
        const float inv = 1.0f / l_i;
        const size_t base = ((size_t)b * TT + qrow) * (NHD * HD) + (size_t)n * HD;
        #pragma unroll
        for (int nt = 0; nt < 4; ++nt) {
            bf16x4 o = { (bf16)(O[nt][0] * inv), (bf16)(O[nt][1] * inv),
                         (bf16)(O[nt][2] * inv), (bf16)(O[nt][3] * inv) };
            *(bf16x4*)(AO + base + (nt << 4) + (quad << 2)) = o;
        }
    }
}

// ---------------------------------------------------------------------------
extern "C" void kernel_launch(void* const* d_in, const int* in_sizes, int n_in,
                              void* d_out, int out_size, void* d_ws, size_t ws_size,
                              hipStream_t stream)
{
    const float* X   = (const float*)d_in[0];
    const int*   msk = (const int*)d_in[1];
    const float* wq  = (const float*)d_in[2];
    const float* bq  = (const float*)d_in[3];
    const float* wk  = (const float*)d_in[4];
    const float* bk  = (const float*)d_in[5];
    const float* wv  = (const float*)d_in[6];
    const float* bv  = (const float*)d_in[7];
    const float* wo  = (const float*)d_in[8];
    const float* bo  = (const float*)d_in[9];
    const float* pds = (const float*)d_in[10];
    float* out = (float*)d_out;

    bf16* ws   = (bf16*)d_ws;
    bf16* Xh   = ws;                      // 4M  (later aliased by AO)
    bf16* Xl   = ws + 4194304;            // 4M  (later aliased by Vt)
    bf16* WQKh = ws + 8388608;            // 2M  [2048 nh'][1024 d]
    bf16* WQKl = ws + 10485760;           // 2M
    bf16* Wvh  = ws + 12582912;           // 1M  [nh][d]
    bf16* Wob  = ws + 13631488;           // 1M  [d][nh]
    bf16* Qhb  = ws + 14680064;           // 4M  [b][n][t][h]
    bf16* Qlb  = ws + 18874368;
    bf16* Khb  = ws + 23068672;
    bf16* Klb  = ws + 27262976;
    unsigned* mbits = (unsigned*)(ws + 31457280);   // 1 MB
    bf16* Vtb  = Xl;                      // alias: Xl dead after QK-GEMM
    bf16* AOb  = Xh;                      // alias: Xh dead after V-GEMM

    dim3 blk(256);

    prep_all<<<40960, blk, 0, stream>>>(X, msk, wq, wk, wv, wo,
                                        Xh, Xl, WQKh, WQKl, Wvh, Wob, mbits);

    // QK projection: M=4096, N=2048, 3-term split in one K-sweep
    gemm_qk<<<dim3(16, 32), blk, 0, stream>>>(
        Xh, Xl, WQKh, WQKl, bq, bk, pds, Qhb, Qlb, Khb, Klb);

    // V projection, transposed output: M=1024 (nh), N=4096 (bt), K=1024
    gemm128<<<dim3(32, 8), blk, 0, stream>>>(
        Wvh, Xh, bv, Vtb, nullptr, 1);

    dim3 ga(TT / 64, BB * NHD);   // (32, 32)
    attn_mfma<<<ga, blk, 0, stream>>>(Qhb, Qlb, Khb, Klb, Vtb, mbits, AOb);

    // output projection: M=4096, N=1024, K=1024, fp32 out
    gemm128<<<dim3(8, 32), blk, 0, stream>>>(
        AOb, Wob, bo, nullptr, out, 2);
}

// Round 8
// 319.434 us; speedup vs baseline: 3.6460x; 1.0783x over previous
//
#include <hip/hip_runtime.h>
#include <math.h>

typedef __bf16 bf16;
typedef __attribute__((ext_vector_type(8))) __bf16 bf16x8;
typedef __attribute__((ext_vector_type(4))) __bf16 bf16x4;
typedef __attribute__((ext_vector_type(4))) float f32x4;

#define BB 2
#define TT 2048
#define DD 1024
#define NHD 16
#define HD 64
#define MM (BB*TT)          // 4096
#define LOG2E_F 1.442695041f
#define NEGINF_F (-1.0e9f)

// async global->LDS, 16B per lane; LDS dest must be wave-uniform base
__device__ __forceinline__ void gld16(const bf16* g, bf16* l)
{
    __builtin_amdgcn_global_load_lds(
        (const __attribute__((address_space(1))) unsigned int*)g,
        (__attribute__((address_space(3))) unsigned int*)l, 16, 0, 0);
}

// ---------------------------------------------------------------------------
// fused prep: [0,4096) split_x; [4096,8192) weight transpose/convert;
// [8192,40960) mask->bitmask.
// ---------------------------------------------------------------------------
__global__ __launch_bounds__(256)
void prep_all(const float* __restrict__ X, const int* __restrict__ m,
              const float* __restrict__ wq, const float* __restrict__ wk,
              const float* __restrict__ wv, const float* __restrict__ wo,
              bf16* __restrict__ Xh, bf16* __restrict__ Xl,
              bf16* __restrict__ qkh, bf16* __restrict__ qkl,
              bf16* __restrict__ vh, bf16* __restrict__ ob,
              unsigned* __restrict__ bits)
{
    __shared__ float tile[32][33];
    const int bid = blockIdx.x;
    const int t   = threadIdx.x;

    if (bid < 4096) {                         // split X -> hi/lo
        int i = bid * 256 + t;
        float4 v = ((const float4*)X)[i];
        float f[4] = {v.x, v.y, v.z, v.w};
        bf16x4 h, l;
        #pragma unroll
        for (int j = 0; j < 4; ++j) {
            bf16 hh = (bf16)f[j];
            h[j] = hh;
            l[j] = (bf16)(f[j] - (float)hh);
        }
        *(bf16x4*)(Xh + (size_t)i * 4) = h;
        *(bf16x4*)(Xl + (size_t)i * 4) = l;
        return;
    }
    if (bid < 8192) {                         // weights
        const int idx = bid - 4096;
        const int z   = idx >> 10;            // 0:wq 1:wk 2:wv 3:wo
        const int bx  = (idx & 31) << 5;      // nh block
        const int by  = ((idx >> 5) & 31) << 5;  // d block
        const int r   = t >> 3;
        const int c4  = (t & 7) << 2;
        if (z == 3) {
            float4 v = *(const float4*)(wo + (size_t)(by + r) * 1024 + bx + c4);
            bf16x4 o = { (bf16)v.x, (bf16)v.y, (bf16)v.z, (bf16)v.w };
            *(bf16x4*)(ob + (size_t)(by + r) * 1024 + bx + c4) = o;
            return;
        }
        const float* src = (z == 0) ? wq : ((z == 1) ? wk : wv);
        bf16* oh = (z == 0) ? qkh : ((z == 1) ? qkh + 1048576 : vh);
        bf16* ol = (z == 0) ? qkl : ((z == 1) ? qkl + 1048576 : nullptr);
        float4 v = *(const float4*)(src + (size_t)(by + r) * 1024 + bx + c4);
        tile[r][c4+0] = v.x; tile[r][c4+1] = v.y;
        tile[r][c4+2] = v.z; tile[r][c4+3] = v.w;
        __syncthreads();
        bf16x4 hv, lv;
        #pragma unroll
        for (int j = 0; j < 4; ++j) {
            float f = tile[c4 + j][r];
            bf16 h = (bf16)f;
            hv[j] = h;
            lv[j] = (bf16)(f - (float)h);
        }
        *(bf16x4*)(oh + (size_t)(bx + r) * 1024 + by + c4) = hv;
        if (ol)
            *(bf16x4*)(ol + (size_t)(bx + r) * 1024 + by + c4) = lv;
        return;
    }
    {                                         // pack mask
        int i = (bid - 8192) * 256 + t;
        int lane = t & 63;
        int v = m[i];
        unsigned long long bl = __ballot(v != 0);
        if ((lane & 31) == 0)
            bits[i >> 5] = (unsigned)(bl >> (lane & 32));
    }
}

// ---------------------------------------------------------------------------
// Fused projection GEMM (768 blocks):
//  [0,512): QK — single K-sweep split (Xh*Wh + Xh*Wl + Xl*Wh), 128x128, BK=32;
//           col<1024 -> Q (scaled, exp2-domain), else K; split hi/lo out.
//  [512,768): V — C^T = Wvh · Xh^T, out Vt[b][nh][t] bf16 + bias.
// ---------------------------------------------------------------------------
__global__ __launch_bounds__(256)
void gemm_proj(const bf16* __restrict__ Xh, const bf16* __restrict__ Xl,
               const bf16* __restrict__ Wh, const bf16* __restrict__ Wl,
               const bf16* __restrict__ Wvh,
               const float* __restrict__ bq, const float* __restrict__ bk,
               const float* __restrict__ bv, const float* __restrict__ pds,
               bf16* __restrict__ oQh, bf16* __restrict__ oQl,
               bf16* __restrict__ oKh, bf16* __restrict__ oKl,
               bf16* __restrict__ oVt)
{
    __shared__ bf16 S[4][128 * 32];   // QK: Ah/Al/Bh/Bl ; V: uses S[0],S[2]

    const int bid  = blockIdx.x;
    const int t    = threadIdx.x;
    const int lane = t & 63;
    const int w    = t >> 6;
    const int quad = lane >> 4, l15 = lane & 15;
    const int wm   = (w >> 1) << 6;
    const int wn   = (w & 1)  << 6;

    const int jr0 = ((w * 2 + 0) << 4) + (lane >> 2);
    const int jr1 = ((w * 2 + 1) << 4) + (lane >> 2);
    const int kch = (lane & 3) << 3;
    const int off0 = (w * 2 + 0) * 512;
    const int off1 = (w * 2 + 1) * 512;

    if (bid < 512) {
        // ---------------- QK path ----------------
        const int m0 = (bid >> 4) << 7;
        const int n0 = (bid & 15) << 7;
        bf16* Ah = S[0]; bf16* Al = S[1]; bf16* Bh = S[2]; bf16* Bl = S[3];

        const bf16* pAh0 = Xh + (size_t)(m0 + jr0) * DD + kch;
        const bf16* pAh1 = Xh + (size_t)(m0 + jr1) * DD + kch;
        const bf16* pAl0 = Xl + (size_t)(m0 + jr0) * DD + kch;
        const bf16* pAl1 = Xl + (size_t)(m0 + jr1) * DD + kch;
        const bf16* pBh0 = Wh + (size_t)(n0 + jr0) * DD + kch;
        const bf16* pBh1 = Wh + (size_t)(n0 + jr1) * DD + kch;
        const bf16* pBl0 = Wl + (size_t)(n0 + jr0) * DD + kch;
        const bf16* pBl1 = Wl + (size_t)(n0 + jr1) * DD + kch;

        f32x4 acc[4][4] = {};

        for (int k0 = 0; k0 < DD; k0 += 32) {
            __syncthreads();
            gld16(pAh0 + k0, Ah + off0);  gld16(pAh1 + k0, Ah + off1);
            gld16(pAl0 + k0, Al + off0);  gld16(pAl1 + k0, Al + off1);
            gld16(pBh0 + k0, Bh + off0);  gld16(pBh1 + k0, Bh + off1);
            gld16(pBl0 + k0, Bl + off0);  gld16(pBl1 + k0, Bl + off1);
            __syncthreads();

            bf16x8 ah[4], bh[4];
            #pragma unroll
            for (int mt = 0; mt < 4; ++mt)
                ah[mt] = *(const bf16x8*)(Ah + (wm + (mt << 4) + l15) * 32 + (quad << 3));
            #pragma unroll
            for (int nt = 0; nt < 4; ++nt)
                bh[nt] = *(const bf16x8*)(Bh + (wn + (nt << 4) + l15) * 32 + (quad << 3));
            #pragma unroll
            for (int mt = 0; mt < 4; ++mt)
                #pragma unroll
                for (int nt = 0; nt < 4; ++nt)
                    acc[mt][nt] = __builtin_amdgcn_mfma_f32_16x16x32_bf16(
                        ah[mt], bh[nt], acc[mt][nt], 0, 0, 0);

            bf16x8 bl[4];
            #pragma unroll
            for (int nt = 0; nt < 4; ++nt)
                bl[nt] = *(const bf16x8*)(Bl + (wn + (nt << 4) + l15) * 32 + (quad << 3));
            #pragma unroll
            for (int mt = 0; mt < 4; ++mt)
                #pragma unroll
                for (int nt = 0; nt < 4; ++nt)
                    acc[mt][nt] = __builtin_amdgcn_mfma_f32_16x16x32_bf16(
                        ah[mt], bl[nt], acc[mt][nt], 0, 0, 0);

            bf16x8 al[4];
            #pragma unroll
            for (int mt = 0; mt < 4; ++mt)
                al[mt] = *(const bf16x8*)(Al + (wm + (mt << 4) + l15) * 32 + (quad << 3));
            #pragma unroll
            for (int mt = 0; mt < 4; ++mt)
                #pragma unroll
                for (int nt = 0; nt < 4; ++nt)
                    acc[mt][nt] = __builtin_amdgcn_mfma_f32_16x16x32_bf16(
                        al[mt], bh[nt], acc[mt][nt], 0, 0, 0);
        }

        #pragma unroll
        for (int nt = 0; nt < 4; ++nt) {
            const int col = n0 + wn + (nt << 4) + l15;
            const int isQ = (col < 1024);
            const int nh  = col & 1023;
            const int n   = nh >> 6, h = nh & 63;
            const float bcol = isQ ? bq[nh] : bk[nh];
            float s = 1.f;
            if (isQ) {
                float x  = pds[h];
                float sp = fmaxf(x, 0.f) + log1pf(expf(-fabsf(x)));  // softplus
                s = (LOG2E_F * LOG2E_F / 8.0f) * sp;  // exp2 domain
            }
            bf16* dH = isQ ? oQh : oKh;
            bf16* dL = isQ ? oQl : oKl;
            #pragma unroll
            for (int mt = 0; mt < 4; ++mt) {
                #pragma unroll
                for (int reg = 0; reg < 4; ++reg) {
                    const int row = m0 + wm + (mt << 4) + (quad << 2) + reg;
                    const int bi  = row >> 11;
                    const int tt  = row & (TT - 1);
                    float val = (acc[mt][nt][reg] + bcol) * s;
                    const size_t idx = (((size_t)bi * NHD + n) * TT + tt) * HD + h;
                    bf16 hi = (bf16)val;
                    dH[idx] = hi;
                    dL[idx] = (bf16)(val - (float)hi);
                }
            }
        }
    } else {
        // ---------------- V path ----------------
        const int idx = bid - 512;
        const int m0  = (idx >> 5) << 7;      // nh tile (8)
        const int n0  = (idx & 31) << 7;      // bt tile (32)
        bf16* As = S[0]; bf16* Bs = S[2];

        const bf16* Ap0 = Wvh + (size_t)(m0 + jr0) * DD + kch;
        const bf16* Ap1 = Wvh + (size_t)(m0 + jr1) * DD + kch;
        const bf16* Bp0 = Xh  + (size_t)(n0 + jr0) * DD + kch;
        const bf16* Bp1 = Xh  + (size_t)(n0 + jr1) * DD + kch;

        f32x4 acc[4][4] = {};

        for (int k0 = 0; k0 < DD; k0 += 32) {
            __syncthreads();
            gld16(Ap0 + k0, As + off0);
            gld16(Ap1 + k0, As + off1);
            gld16(Bp0 + k0, Bs + off0);
            gld16(Bp1 + k0, Bs + off1);
            __syncthreads();
            bf16x8 af[4], bfm[4];
            #pragma unroll
            for (int mt = 0; mt < 4; ++mt)
                af[mt] = *(const bf16x8*)(As + (wm + (mt << 4) + l15) * 32 + (quad << 3));
            #pragma unroll
            for (int nt = 0; nt < 4; ++nt)
                bfm[nt] = *(const bf16x8*)(Bs + (wn + (nt << 4) + l15) * 32 + (quad << 3));
            #pragma unroll
            for (int mt = 0; mt < 4; ++mt)
                #pragma unroll
                for (int nt = 0; nt < 4; ++nt)
                    acc[mt][nt] = __builtin_amdgcn_mfma_f32_16x16x32_bf16(
                        af[mt], bfm[nt], acc[mt][nt], 0, 0, 0);
        }

        #pragma unroll
        for (int nt = 0; nt < 4; ++nt) {
            const int col = n0 + wn + (nt << 4) + l15;   // bt
            const int bi  = col >> 11;
            const int tt  = col & (TT - 1);
            #pragma unroll
            for (int mt = 0; mt < 4; ++mt) {
                #pragma unroll
                for (int reg = 0; reg < 4; ++reg) {
                    const int row = m0 + wm + (mt << 4) + (quad << 2) + reg;  // nh
                    float val = acc[mt][nt][reg] + bv[row];
                    oVt[((size_t)bi * 1024 + row) * TT + tt] = (bf16)val;
                }
            }
        }
    }
}

// ---------------------------------------------------------------------------
// Output projection GEMM: 128x128, BK=32, fp32 out + bias.
// ---------------------------------------------------------------------------
__global__ __launch_bounds__(256)
void gemm_out(const bf16* __restrict__ A, const bf16* __restrict__ Bt,
              const float* __restrict__ bias, float* __restrict__ oF)
{
    __shared__ bf16 As[128 * 32];
    __shared__ bf16 Bs[128 * 32];

    const int t    = threadIdx.x;
    const int lane = t & 63;
    const int w    = t >> 6;
    const int quad = lane >> 4, l15 = lane & 15;
    const int m0   = blockIdx.y << 7;
    const int n0   = blockIdx.x << 7;
    const int wm   = (w >> 1) << 6;
    const int wn   = (w & 1)  << 6;

    const int jr0 = ((w * 2 + 0) << 4) + (lane >> 2);
    const int jr1 = ((w * 2 + 1) << 4) + (lane >> 2);
    const int kch = (lane & 3) << 3;

    bf16* lA0 = As + (w * 2 + 0) * 512;
    bf16* lA1 = As + (w * 2 + 1) * 512;
    bf16* lB0 = Bs + (w * 2 + 0) * 512;
    bf16* lB1 = Bs + (w * 2 + 1) * 512;

    const bf16* Ap0 = A  + (size_t)(m0 + jr0) * DD + kch;
    const bf16* Ap1 = A  + (size_t)(m0 + jr1) * DD + kch;
    const bf16* Bp0 = Bt + (size_t)(n0 + jr0) * DD + kch;
    const bf16* Bp1 = Bt + (size_t)(n0 + jr1) * DD + kch;

    f32x4 acc[4][4] = {};

    for (int k0 = 0; k0 < DD; k0 += 32) {
        __syncthreads();
        gld16(Ap0 + k0, lA0);
        gld16(Ap1 + k0, lA1);
        gld16(Bp0 + k0, lB0);
        gld16(Bp1 + k0, lB1);
        __syncthreads();
        bf16x8 af[4], bfm[4];
        #pragma unroll
        for (int mt = 0; mt < 4; ++mt)
            af[mt] = *(const bf16x8*)(As + (wm + (mt << 4) + l15) * 32 + (quad << 3));
        #pragma unroll
        for (int nt = 0; nt < 4; ++nt)
            bfm[nt] = *(const bf16x8*)(Bs + (wn + (nt << 4) + l15) * 32 + (quad << 3));
        #pragma unroll
        for (int mt = 0; mt < 4; ++mt)
            #pragma unroll
            for (int nt = 0; nt < 4; ++nt)
                acc[mt][nt] = __builtin_amdgcn_mfma_f32_16x16x32_bf16(
                    af[mt], bfm[nt], acc[mt][nt], 0, 0, 0);
    }

    #pragma unroll
    for (int nt = 0; nt < 4; ++nt) {
        const int col = n0 + wn + (nt << 4) + l15;
        const float bcol = bias[col];
        #pragma unroll
        for (int mt = 0; mt < 4; ++mt) {
            #pragma unroll
            for (int reg = 0; reg < 4; ++reg) {
                const int row = m0 + wm + (mt << 4) + (quad << 2) + reg;
                oF[(size_t)row * DD + col] = acc[mt][nt][reg] + bcol;
            }
        }
    }
}

// ---------------------------------------------------------------------------
// MFMA flash attention, transposed-score formulation (S^T = K·Q^T).
// 512 threads = 8 waves, q-tile 128 (16 q per wave). K hi/lo + Vt in LDS,
// staged once per 128 q. Split-bf16 scores; exp2-domain softmax.
// ---------------------------------------------------------------------------
__global__ __launch_bounds__(512)
void attn_mfma(const bf16* __restrict__ Qh, const bf16* __restrict__ Ql,
               const bf16* __restrict__ Kh, const bf16* __restrict__ Kl,
               const bf16* __restrict__ Vt, const unsigned* __restrict__ mbits,
               bf16* __restrict__ AO)
{
    __shared__ bf16 Ksh[64][72];
    __shared__ bf16 Ksl[64][72];
    __shared__ bf16 Vts[64][72];       // [h][s]
    __shared__ bf16 Ps[8][16][72];     // per-wave P^T-as-[q][s]
    __shared__ unsigned msk[128][2];

    const int t    = threadIdx.x;
    const int lane = t & 63;
    const int w    = t >> 6;           // 0..7
    const int quad = lane >> 4, l15 = lane & 15;
    const int bn   = blockIdx.y;
    const int b    = bn >> 4, n = bn & 15;
    const int q0   = blockIdx.x << 7;  // 128 q per block

    const bf16* Qbh = Qh + (size_t)bn * TT * HD;
    const bf16* Qbl = Ql + (size_t)bn * TT * HD;
    const bf16* Kbh = Kh + (size_t)bn * TT * HD;
    const bf16* Kbl = Kl + (size_t)bn * TT * HD;
    const bf16* Vtb = Vt + (size_t)bn * HD * TT;

    // Q fragments (B-operand: n=q=l15, k=h) — registers, loaded once
    const int qrow = q0 + (w << 4) + l15;
    bf16x8 qfh[2], qfl[2];
    qfh[0] = *(const bf16x8*)(Qbh + (size_t)qrow * HD + (quad << 3));
    qfh[1] = *(const bf16x8*)(Qbh + (size_t)qrow * HD + 32 + (quad << 3));
    qfl[0] = *(const bf16x8*)(Qbl + (size_t)qrow * HD + (quad << 3));
    qfl[1] = *(const bf16x8*)(Qbl + (size_t)qrow * HD + 32 + (quad << 3));

    f32x4 O[4];                         // O^T: row h=nt*16+quad*4+reg, col q=l15
    #pragma unroll
    for (int i = 0; i < 4; ++i) O[i] = (f32x4){0.f,0.f,0.f,0.f};
    float m_i = -INFINITY;
    float l_i = 0.f;

    // staging map: 512 threads x bf16x8 = 8KB per array
    const int rS = t >> 3, cS = (t & 7) << 3;

    for (int kb = 0; kb < TT; kb += 64) {
        // prefetch globals into regs
        bf16x8 khv = *(const bf16x8*)(Kbh + (size_t)(kb + rS) * HD + cS);
        bf16x8 klv = *(const bf16x8*)(Kbl + (size_t)(kb + rS) * HD + cS);
        bf16x8 vv  = *(const bf16x8*)(Vtb + (size_t)rS * TT + kb + cS);
        unsigned mw = 0;
        if (t < 256)
            mw = mbits[((size_t)b * TT + q0 + (t >> 1)) * (TT / 32) + (kb >> 5) + (t & 1)];

        __syncthreads();   // previous tile fully consumed
        *(bf16x8*)&Ksh[rS][cS] = khv;
        *(bf16x8*)&Ksl[rS][cS] = klv;
        *(bf16x8*)&Vts[rS][cS] = vv;
        if (t < 256) msk[t >> 1][t & 1] = mw;
        __syncthreads();

        // S^T = K Q^T (rows s, cols q), split: Kh*Qh + Kl*Qh + Kh*Ql
        f32x4 s_acc[4];
        #pragma unroll
        for (int i = 0; i < 4; ++i) s_acc[i] = (f32x4){0.f,0.f,0.f,0.f};
        #pragma unroll
        for (int k2 = 0; k2 < 2; ++k2) {
            #pragma unroll
            for (int nt = 0; nt < 4; ++nt) {
                bf16x8 bkh = *(const bf16x8*)&Ksh[(nt << 4) + l15][(k2 << 5) + (quad << 3)];
                bf16x8 bkl = *(const bf16x8*)&Ksl[(nt << 4) + l15][(k2 << 5) + (quad << 3)];
                s_acc[nt] = __builtin_amdgcn_mfma_f32_16x16x32_bf16(bkh, qfh[k2], s_acc[nt], 0, 0, 0);
                s_acc[nt] = __builtin_amdgcn_mfma_f32_16x16x32_bf16(bkl, qfh[k2], s_acc[nt], 0, 0, 0);
                s_acc[nt] = __builtin_amdgcn_mfma_f32_16x16x32_bf16(bkh, qfl[k2], s_acc[nt], 0, 0, 0);
            }
        }

        // per-lane softmax over s (16 local vals + cross-quad shuffles)
        const unsigned w0 = msk[(w << 4) + l15][0];
        const unsigned w1 = msk[(w << 4) + l15][1];
        float sv[16];
        #pragma unroll
        for (int nt = 0; nt < 4; ++nt) {
            const unsigned word = (nt & 2) ? w1 : w0;
            #pragma unroll
            for (int reg = 0; reg < 4; ++reg) {
                const int bit = ((nt & 1) << 4) + (quad << 2) + reg;
                sv[nt * 4 + reg] = ((word >> bit) & 1u) ? s_acc[nt][reg] : NEGINF_F;
            }
        }
        float mx = sv[0];
        #pragma unroll
        for (int i = 1; i < 16; ++i) mx = fmaxf(mx, sv[i]);
        mx = fmaxf(mx, __shfl_xor(mx, 16));
        mx = fmaxf(mx, __shfl_xor(mx, 32));
        const float mnew  = fmaxf(m_i, mx);
        const float alpha = exp2f(m_i - mnew);   // exp2(-inf)=0 first tile
        float p[16], sum = 0.f;
        #pragma unroll
        for (int i = 0; i < 16; ++i) { p[i] = exp2f(sv[i] - mnew); sum += p[i]; }
        sum += __shfl_xor(sum, 16);
        sum += __shfl_xor(sum, 32);
        l_i = l_i * alpha + sum;
        m_i = mnew;
        #pragma unroll
        for (int nt = 0; nt < 4; ++nt) {
            O[nt][0] *= alpha; O[nt][1] *= alpha;
            O[nt][2] *= alpha; O[nt][3] *= alpha;
            bf16x4 pv = { (bf16)p[nt * 4 + 0], (bf16)p[nt * 4 + 1],
                          (bf16)p[nt * 4 + 2], (bf16)p[nt * 4 + 3] };
            *(bf16x4*)&Ps[w][l15][(nt << 4) + (quad << 2)] = pv;
        }

        // O^T += Vt P^T  (A=Vt rows h, B=P rows q)
        #pragma unroll
        for (int s2 = 0; s2 < 2; ++s2) {
            bf16x8 ap = *(const bf16x8*)&Ps[w][l15][(s2 << 5) + (quad << 3)];
            #pragma unroll
            for (int nt = 0; nt < 4; ++nt) {
                bf16x8 bv = *(const bf16x8*)&Vts[(nt << 4) + l15][(s2 << 5) + (quad << 3)];
                O[nt] = __builtin_amdgcn_mfma_f32_16x16x32_bf16(bv, ap, O[nt], 0, 0, 0);
            }
        }
    }

    // normalize + write AO (bf16, [B*T][N*H]); lane owns col q, rows h
    {
        const float inv = 1.0f / l_i;
        const size_t base = ((size_t)b * TT + qrow) * (NHD * HD) + (size_t)n * HD;
        #pragma unroll
        for (int nt = 0; nt < 4; ++nt) {
            bf16x4 o = { (bf16)(O[nt][0] * inv), (bf16)(O[nt][1] * inv),
                         (bf16)(O[nt][2] * inv), (bf16)(O[nt][3] * inv) };
            *(bf16x4*)(AO + base + (nt << 4) + (quad << 2)) = o;
        }
    }
}

// ---------------------------------------------------------------------------
extern "C" void kernel_launch(void* const* d_in, const int* in_sizes, int n_in,
                              void* d_out, int out_size, void* d_ws, size_t ws_size,
                              hipStream_t stream)
{
    const float* X   = (const float*)d_in[0];
    const int*   msk = (const int*)d_in[1];
    const float* wq  = (const float*)d_in[2];
    const float* bq  = (const float*)d_in[3];
    const float* wk  = (const float*)d_in[4];
    const float* bk  = (const float*)d_in[5];
    const float* wv  = (const float*)d_in[6];
    const float* bv  = (const float*)d_in[7];
    const float* wo  = (const float*)d_in[8];
    const float* bo  = (const float*)d_in[9];
    const float* pds = (const float*)d_in[10];
    float* out = (float*)d_out;

    bf16* ws   = (bf16*)d_ws;
    bf16* Xh   = ws;                      // 4M  (later aliased by AO)
    bf16* Xl   = ws + 4194304;            // 4M  (later aliased by Vt)
    bf16* WQKh = ws + 8388608;            // 2M  [2048 nh'][1024 d]
    bf16* WQKl = ws + 10485760;           // 2M
    bf16* Wvh  = ws + 12582912;           // 1M  [nh][d]
    bf16* Wob  = ws + 13631488;           // 1M  [d][nh]
    bf16* Qhb  = ws + 14680064;           // 4M  [b][n][t][h]
    bf16* Qlb  = ws + 18874368;
    bf16* Khb  = ws + 23068672;
    bf16* Klb  = ws + 27262976;
    unsigned* mbits = (unsigned*)(ws + 31457280);   // 1 MB
    bf16* Vtb  = Xl;                      // alias: Xl dead after proj
    bf16* AOb  = Xh;                      // alias: Xh dead after proj

    dim3 blk(256);

    prep_all<<<40960, blk, 0, stream>>>(X, msk, wq, wk, wv, wo,
                                        Xh, Xl, WQKh, WQKl, Wvh, Wob, mbits);

    // fused QK + V projections (NOTE: V path writes Vtb which aliases Xl;
    // V path reads only Wvh and Xh, QK path reads Xl — Xl reads and Vtb
    // writes target different 128-row bt-tiles only within V blocks; QK
    // blocks read Xl rows for their own m-tile. Alias is safe ONLY if V
    // writes don't race QK's Xl reads — they do race in one dispatch!
    // So V writes to a separate buffer instead:
    gemm_proj<<<768, blk, 0, stream>>>(
        Xh, Xl, WQKh, WQKl, Wvh, bq, bk, bv, pds,
        Qhb, Qlb, Khb, Klb, (bf16*)(ws + 32505856));   // Vt in fresh region

    dim3 ga(TT / 128, BB * NHD);   // (16, 32)
    attn_mfma<<<ga, dim3(512), 0, stream>>>(
        Qhb, Qlb, Khb, Klb, (bf16*)(ws + 32505856), mbits, AOb);

    // output projection: M=4096, N=1024, K=1024, fp32 out
    gemm_out<<<dim3(8, 32), blk, 0, stream>>>(AOb, Wob, bo, out);
}

// Round 9
// 309.318 us; speedup vs baseline: 3.7652x; 1.0327x over previous
//
#include <hip/hip_runtime.h>
#include <math.h>

typedef __bf16 bf16;
typedef __attribute__((ext_vector_type(8))) __bf16 bf16x8;
typedef __attribute__((ext_vector_type(4))) __bf16 bf16x4;
typedef __attribute__((ext_vector_type(4))) float f32x4;

#define BB 2
#define TT 2048
#define DD 1024
#define NHD 16
#define HD 64
#define MM (BB*TT)          // 4096
#define LOG2E_F 1.442695041f
#define NEGINF_F (-1.0e9f)

// async global->LDS, 16B per lane; LDS dest must be wave-uniform base
__device__ __forceinline__ void gld16(const bf16* g, bf16* l)
{
    __builtin_amdgcn_global_load_lds(
        (const __attribute__((address_space(1))) unsigned int*)g,
        (__attribute__((address_space(3))) unsigned int*)l, 16, 0, 0);
}

// ---------------------------------------------------------------------------
// fused prep: [0,4096) split_x; [4096,8192) weight transpose/convert;
// [8192,12288) mask -> byte-packed bits (8 ints -> 1 byte per thread).
// ---------------------------------------------------------------------------
__global__ __launch_bounds__(256)
void prep_all(const float* __restrict__ X, const int* __restrict__ m,
              const float* __restrict__ wq, const float* __restrict__ wk,
              const float* __restrict__ wv, const float* __restrict__ wo,
              bf16* __restrict__ Xh, bf16* __restrict__ Xl,
              bf16* __restrict__ qkh, bf16* __restrict__ qkl,
              bf16* __restrict__ vh, bf16* __restrict__ ob,
              unsigned char* __restrict__ bits)
{
    __shared__ float tile[32][33];
    const int bid = blockIdx.x;
    const int t   = threadIdx.x;

    if (bid < 4096) {                         // split X -> hi/lo
        int i = bid * 256 + t;
        float4 v = ((const float4*)X)[i];
        float f[4] = {v.x, v.y, v.z, v.w};
        bf16x4 h, l;
        #pragma unroll
        for (int j = 0; j < 4; ++j) {
            bf16 hh = (bf16)f[j];
            h[j] = hh;
            l[j] = (bf16)(f[j] - (float)hh);
        }
        *(bf16x4*)(Xh + (size_t)i * 4) = h;
        *(bf16x4*)(Xl + (size_t)i * 4) = l;
        return;
    }
    if (bid < 8192) {                         // weights
        const int idx = bid - 4096;
        const int z   = idx >> 10;            // 0:wq 1:wk 2:wv 3:wo
        const int bx  = (idx & 31) << 5;      // nh block
        const int by  = ((idx >> 5) & 31) << 5;  // d block
        const int r   = t >> 3;
        const int c4  = (t & 7) << 2;
        if (z == 3) {
            float4 v = *(const float4*)(wo + (size_t)(by + r) * 1024 + bx + c4);
            bf16x4 o = { (bf16)v.x, (bf16)v.y, (bf16)v.z, (bf16)v.w };
            *(bf16x4*)(ob + (size_t)(by + r) * 1024 + bx + c4) = o;
            return;
        }
        const float* src = (z == 0) ? wq : ((z == 1) ? wk : wv);
        bf16* oh = (z == 0) ? qkh : ((z == 1) ? qkh + 1048576 : vh);
        bf16* ol = (z == 0) ? qkl : ((z == 1) ? qkl + 1048576 : nullptr);
        float4 v = *(const float4*)(src + (size_t)(by + r) * 1024 + bx + c4);
        tile[r][c4+0] = v.x; tile[r][c4+1] = v.y;
        tile[r][c4+2] = v.z; tile[r][c4+3] = v.w;
        __syncthreads();
        bf16x4 hv, lv;
        #pragma unroll
        for (int j = 0; j < 4; ++j) {
            float f = tile[c4 + j][r];
            bf16 h = (bf16)f;
            hv[j] = h;
            lv[j] = (bf16)(f - (float)h);
        }
        *(bf16x4*)(oh + (size_t)(bx + r) * 1024 + by + c4) = hv;
        if (ol)
            *(bf16x4*)(ol + (size_t)(bx + r) * 1024 + by + c4) = lv;
        return;
    }
    {                                         // pack mask: 8 ints -> 1 byte
        int i = (bid - 8192) * 256 + t;       // i < 1048576
        const int4* mp = (const int4*)m + (size_t)i * 2;
        int4 a  = mp[0];
        int4 b4 = mp[1];
        unsigned v = (a.x  != 0)       | ((a.y  != 0) << 1)
                   | ((a.z  != 0) << 2) | ((a.w  != 0) << 3)
                   | ((b4.x != 0) << 4) | ((b4.y != 0) << 5)
                   | ((b4.z != 0) << 6) | ((b4.w != 0) << 7);
        bits[i] = (unsigned char)v;
    }
}

// ---------------------------------------------------------------------------
// Fused projection GEMM (768 blocks):
//  [0,512): QK — single K-sweep split (Xh*Wh + Xh*Wl + Xl*Wh), 128x128, BK=32;
//           col<1024 -> Q (scaled, exp2-domain), else K; split hi/lo out.
//  [512,768): V — C^T = Wvh · Xh^T, out Vt[b][nh][t] bf16 + bias.
// ---------------------------------------------------------------------------
__global__ __launch_bounds__(256)
void gemm_proj(const bf16* __restrict__ Xh, const bf16* __restrict__ Xl,
               const bf16* __restrict__ Wh, const bf16* __restrict__ Wl,
               const bf16* __restrict__ Wvh,
               const float* __restrict__ bq, const float* __restrict__ bk,
               const float* __restrict__ bv, const float* __restrict__ pds,
               bf16* __restrict__ oQh, bf16* __restrict__ oQl,
               bf16* __restrict__ oKh, bf16* __restrict__ oKl,
               bf16* __restrict__ oVt)
{
    __shared__ bf16 S[4][128 * 32];   // QK: Ah/Al/Bh/Bl ; V: uses S[0],S[2]

    const int bid  = blockIdx.x;
    const int t    = threadIdx.x;
    const int lane = t & 63;
    const int w    = t >> 6;
    const int quad = lane >> 4, l15 = lane & 15;
    const int wm   = (w >> 1) << 6;
    const int wn   = (w & 1)  << 6;

    const int jr0 = ((w * 2 + 0) << 4) + (lane >> 2);
    const int jr1 = ((w * 2 + 1) << 4) + (lane >> 2);
    const int kch = (lane & 3) << 3;
    const int off0 = (w * 2 + 0) * 512;
    const int off1 = (w * 2 + 1) * 512;

    if (bid < 512) {
        // ---------------- QK path ----------------
        const int m0 = (bid >> 4) << 7;
        const int n0 = (bid & 15) << 7;
        bf16* Ah = S[0]; bf16* Al = S[1]; bf16* Bh = S[2]; bf16* Bl = S[3];

        const bf16* pAh0 = Xh + (size_t)(m0 + jr0) * DD + kch;
        const bf16* pAh1 = Xh + (size_t)(m0 + jr1) * DD + kch;
        const bf16* pAl0 = Xl + (size_t)(m0 + jr0) * DD + kch;
        const bf16* pAl1 = Xl + (size_t)(m0 + jr1) * DD + kch;
        const bf16* pBh0 = Wh + (size_t)(n0 + jr0) * DD + kch;
        const bf16* pBh1 = Wh + (size_t)(n0 + jr1) * DD + kch;
        const bf16* pBl0 = Wl + (size_t)(n0 + jr0) * DD + kch;
        const bf16* pBl1 = Wl + (size_t)(n0 + jr1) * DD + kch;

        f32x4 acc[4][4] = {};

        for (int k0 = 0; k0 < DD; k0 += 32) {
            __syncthreads();
            gld16(pAh0 + k0, Ah + off0);  gld16(pAh1 + k0, Ah + off1);
            gld16(pAl0 + k0, Al + off0);  gld16(pAl1 + k0, Al + off1);
            gld16(pBh0 + k0, Bh + off0);  gld16(pBh1 + k0, Bh + off1);
            gld16(pBl0 + k0, Bl + off0);  gld16(pBl1 + k0, Bl + off1);
            __syncthreads();

            bf16x8 ah[4], bh[4];
            #pragma unroll
            for (int mt = 0; mt < 4; ++mt)
                ah[mt] = *(const bf16x8*)(Ah + (wm + (mt << 4) + l15) * 32 + (quad << 3));
            #pragma unroll
            for (int nt = 0; nt < 4; ++nt)
                bh[nt] = *(const bf16x8*)(Bh + (wn + (nt << 4) + l15) * 32 + (quad << 3));
            #pragma unroll
            for (int mt = 0; mt < 4; ++mt)
                #pragma unroll
                for (int nt = 0; nt < 4; ++nt)
                    acc[mt][nt] = __builtin_amdgcn_mfma_f32_16x16x32_bf16(
                        ah[mt], bh[nt], acc[mt][nt], 0, 0, 0);

            bf16x8 bl[4];
            #pragma unroll
            for (int nt = 0; nt < 4; ++nt)
                bl[nt] = *(const bf16x8*)(Bl + (wn + (nt << 4) + l15) * 32 + (quad << 3));
            #pragma unroll
            for (int mt = 0; mt < 4; ++mt)
                #pragma unroll
                for (int nt = 0; nt < 4; ++nt)
                    acc[mt][nt] = __builtin_amdgcn_mfma_f32_16x16x32_bf16(
                        ah[mt], bl[nt], acc[mt][nt], 0, 0, 0);

            bf16x8 al[4];
            #pragma unroll
            for (int mt = 0; mt < 4; ++mt)
                al[mt] = *(const bf16x8*)(Al + (wm + (mt << 4) + l15) * 32 + (quad << 3));
            #pragma unroll
            for (int mt = 0; mt < 4; ++mt)
                #pragma unroll
                for (int nt = 0; nt < 4; ++nt)
                    acc[mt][nt] = __builtin_amdgcn_mfma_f32_16x16x32_bf16(
                        al[mt], bh[nt], acc[mt][nt], 0, 0, 0);
        }

        #pragma unroll
        for (int nt = 0; nt < 4; ++nt) {
            const int col = n0 + wn + (nt << 4) + l15;
            const int isQ = (col < 1024);
            const int nh  = col & 1023;
            const int n   = nh >> 6, h = nh & 63;
            const float bcol = isQ ? bq[nh] : bk[nh];
            float s = 1.f;
            if (isQ) {
                float x  = pds[h];
                float sp = fmaxf(x, 0.f) + log1pf(expf(-fabsf(x)));  // softplus
                s = (LOG2E_F * LOG2E_F / 8.0f) * sp;  // exp2 domain
            }
            bf16* dH = isQ ? oQh : oKh;
            bf16* dL = isQ ? oQl : oKl;
            #pragma unroll
            for (int mt = 0; mt < 4; ++mt) {
                #pragma unroll
                for (int reg = 0; reg < 4; ++reg) {
                    const int row = m0 + wm + (mt << 4) + (quad << 2) + reg;
                    const int bi  = row >> 11;
                    const int tt  = row & (TT - 1);
                    float val = (acc[mt][nt][reg] + bcol) * s;
                    const size_t idx = (((size_t)bi * NHD + n) * TT + tt) * HD + h;
                    bf16 hi = (bf16)val;
                    dH[idx] = hi;
                    dL[idx] = (bf16)(val - (float)hi);
                }
            }
        }
    } else {
        // ---------------- V path ----------------
        const int idx = bid - 512;
        const int m0  = (idx >> 5) << 7;      // nh tile (8)
        const int n0  = (idx & 31) << 7;      // bt tile (32)
        bf16* As = S[0]; bf16* Bs = S[2];

        const bf16* Ap0 = Wvh + (size_t)(m0 + jr0) * DD + kch;
        const bf16* Ap1 = Wvh + (size_t)(m0 + jr1) * DD + kch;
        const bf16* Bp0 = Xh  + (size_t)(n0 + jr0) * DD + kch;
        const bf16* Bp1 = Xh  + (size_t)(n0 + jr1) * DD + kch;

        f32x4 acc[4][4] = {};

        for (int k0 = 0; k0 < DD; k0 += 32) {
            __syncthreads();
            gld16(Ap0 + k0, As + off0);
            gld16(Ap1 + k0, As + off1);
            gld16(Bp0 + k0, Bs + off0);
            gld16(Bp1 + k0, Bs + off1);
            __syncthreads();
            bf16x8 af[4], bfm[4];
            #pragma unroll
            for (int mt = 0; mt < 4; ++mt)
                af[mt] = *(const bf16x8*)(As + (wm + (mt << 4) + l15) * 32 + (quad << 3));
            #pragma unroll
            for (int nt = 0; nt < 4; ++nt)
                bfm[nt] = *(const bf16x8*)(Bs + (wn + (nt << 4) + l15) * 32 + (quad << 3));
            #pragma unroll
            for (int mt = 0; mt < 4; ++mt)
                #pragma unroll
                for (int nt = 0; nt < 4; ++nt)
                    acc[mt][nt] = __builtin_amdgcn_mfma_f32_16x16x32_bf16(
                        af[mt], bfm[nt], acc[mt][nt], 0, 0, 0);
        }

        #pragma unroll
        for (int nt = 0; nt < 4; ++nt) {
            const int col = n0 + wn + (nt << 4) + l15;   // bt
            const int bi  = col >> 11;
            const int tt  = col & (TT - 1);
            #pragma unroll
            for (int mt = 0; mt < 4; ++mt) {
                #pragma unroll
                for (int reg = 0; reg < 4; ++reg) {
                    const int row = m0 + wm + (mt << 4) + (quad << 2) + reg;  // nh
                    float val = acc[mt][nt][reg] + bv[row];
                    oVt[((size_t)bi * 1024 + row) * TT + tt] = (bf16)val;
                }
            }
        }
    }
}

// ---------------------------------------------------------------------------
// Output projection GEMM: 128x64 tile, 512 blocks (2/CU), BK=32, fp32 out.
// ---------------------------------------------------------------------------
__global__ __launch_bounds__(256)
void gemm_out(const bf16* __restrict__ A, const bf16* __restrict__ Bt,
              const float* __restrict__ bias, float* __restrict__ oF)
{
    __shared__ bf16 As[128 * 32];
    __shared__ bf16 Bs[64 * 32];

    const int t    = threadIdx.x;
    const int lane = t & 63;
    const int w    = t >> 6;
    const int quad = lane >> 4, l15 = lane & 15;
    const int m0   = blockIdx.y << 7;
    const int n0   = blockIdx.x << 6;
    const int wm   = (w >> 1) << 6;
    const int wn   = (w & 1)  << 5;

    const int jr0 = ((w * 2 + 0) << 4) + (lane >> 2);
    const int jr1 = ((w * 2 + 1) << 4) + (lane >> 2);
    const int jrB = (w << 4) + (lane >> 2);
    const int kch = (lane & 3) << 3;

    bf16* lA0 = As + (w * 2 + 0) * 512;
    bf16* lA1 = As + (w * 2 + 1) * 512;
    bf16* lB  = Bs + w * 512;

    const bf16* Ap0 = A  + (size_t)(m0 + jr0) * DD + kch;
    const bf16* Ap1 = A  + (size_t)(m0 + jr1) * DD + kch;
    const bf16* Bp  = Bt + (size_t)(n0 + jrB) * DD + kch;

    f32x4 acc[4][2] = {};

    for (int k0 = 0; k0 < DD; k0 += 32) {
        __syncthreads();
        gld16(Ap0 + k0, lA0);
        gld16(Ap1 + k0, lA1);
        gld16(Bp + k0, lB);
        __syncthreads();
        bf16x8 af[4], bfm[2];
        #pragma unroll
        for (int mt = 0; mt < 4; ++mt)
            af[mt] = *(const bf16x8*)(As + (wm + (mt << 4) + l15) * 32 + (quad << 3));
        #pragma unroll
        for (int nt = 0; nt < 2; ++nt)
            bfm[nt] = *(const bf16x8*)(Bs + (wn + (nt << 4) + l15) * 32 + (quad << 3));
        #pragma unroll
        for (int mt = 0; mt < 4; ++mt)
            #pragma unroll
            for (int nt = 0; nt < 2; ++nt)
                acc[mt][nt] = __builtin_amdgcn_mfma_f32_16x16x32_bf16(
                    af[mt], bfm[nt], acc[mt][nt], 0, 0, 0);
    }

    #pragma unroll
    for (int nt = 0; nt < 2; ++nt) {
        const int col = n0 + wn + (nt << 4) + l15;
        const float bcol = bias[col];
        #pragma unroll
        for (int mt = 0; mt < 4; ++mt) {
            #pragma unroll
            for (int reg = 0; reg < 4; ++reg) {
                const int row = m0 + wm + (mt << 4) + (quad << 2) + reg;
                oF[(size_t)row * DD + col] = acc[mt][nt][reg] + bcol;
            }
        }
    }
}

// ---------------------------------------------------------------------------
// MFMA flash attention, transposed-score formulation (S^T = K·Q^T).
// 512 threads, q-tile 128. XOR-swizzled staging lane map (8-way -> 2-way
// LDS write conflicts). Mask read as one ull per q-row (broadcast).
// ---------------------------------------------------------------------------
__global__ __launch_bounds__(512)
void attn_mfma(const bf16* __restrict__ Qh, const bf16* __restrict__ Ql,
               const bf16* __restrict__ Kh, const bf16* __restrict__ Kl,
               const bf16* __restrict__ Vt,
               const unsigned long long* __restrict__ mb64,
               bf16* __restrict__ AO)
{
    __shared__ bf16 Ksh[64][72];
    __shared__ bf16 Ksl[64][72];
    __shared__ bf16 Vts[64][72];       // [h][s]
    __shared__ bf16 Ps[8][16][72];     // per-wave P^T-as-[q][s]
    __shared__ unsigned long long msk64[128];

    const int t    = threadIdx.x;
    const int lane = t & 63;
    const int w    = t >> 6;           // 0..7
    const int quad = lane >> 4, l15 = lane & 15;
    const int bn   = blockIdx.y;
    const int b    = bn >> 4, n = bn & 15;
    const int q0   = blockIdx.x << 7;  // 128 q per block

    const bf16* Qbh = Qh + (size_t)bn * TT * HD;
    const bf16* Qbl = Ql + (size_t)bn * TT * HD;
    const bf16* Kbh = Kh + (size_t)bn * TT * HD;
    const bf16* Kbl = Kl + (size_t)bn * TT * HD;
    const bf16* Vtb = Vt + (size_t)bn * HD * TT;

    // Q fragments (B-operand: n=q=l15, k=h) — registers, loaded once
    const int qrow = q0 + (w << 4) + l15;
    bf16x8 qfh[2], qfl[2];
    qfh[0] = *(const bf16x8*)(Qbh + (size_t)qrow * HD + (quad << 3));
    qfh[1] = *(const bf16x8*)(Qbh + (size_t)qrow * HD + 32 + (quad << 3));
    qfl[0] = *(const bf16x8*)(Qbl + (size_t)qrow * HD + (quad << 3));
    qfl[1] = *(const bf16x8*)(Qbl + (size_t)qrow * HD + 32 + (quad << 3));

    f32x4 O[4];                         // O^T: row h=nt*16+quad*4+reg, col q=l15
    #pragma unroll
    for (int i = 0; i < 4; ++i) O[i] = (f32x4){0.f,0.f,0.f,0.f};
    float m_i = -INFINITY;
    float l_i = 0.f;

    // swizzled staging map: row rS, chunk (t&7)^(rS&7) -> write bank 2-way max
    const int rS = t >> 3;                       // 0..63
    const int cS = (((t & 7) ^ (rS & 7)) << 3);  // swizzled elem offset

    for (int kb = 0; kb < TT; kb += 64) {
        // prefetch globals into regs
        bf16x8 khv = *(const bf16x8*)(Kbh + (size_t)(kb + rS) * HD + cS);
        bf16x8 klv = *(const bf16x8*)(Kbl + (size_t)(kb + rS) * HD + cS);
        bf16x8 vv  = *(const bf16x8*)(Vtb + (size_t)rS * TT + kb + cS);
        unsigned long long mw = 0;
        if (t < 128)
            mw = mb64[((size_t)b * TT + q0 + t) * (TT / 64) + (kb >> 6)];

        __syncthreads();   // previous tile fully consumed
        *(bf16x8*)&Ksh[rS][cS] = khv;
        *(bf16x8*)&Ksl[rS][cS] = klv;
        *(bf16x8*)&Vts[rS][cS] = vv;
        if (t < 128) msk64[t] = mw;
        __syncthreads();

        // S^T = K Q^T (rows s, cols q), split: Kh*Qh + Kl*Qh + Kh*Ql
        f32x4 s_acc[4];
        #pragma unroll
        for (int i = 0; i < 4; ++i) s_acc[i] = (f32x4){0.f,0.f,0.f,0.f};
        #pragma unroll
        for (int k2 = 0; k2 < 2; ++k2) {
            #pragma unroll
            for (int nt = 0; nt < 4; ++nt) {
                bf16x8 bkh = *(const bf16x8*)&Ksh[(nt << 4) + l15][(k2 << 5) + (quad << 3)];
                bf16x8 bkl = *(const bf16x8*)&Ksl[(nt << 4) + l15][(k2 << 5) + (quad << 3)];
                s_acc[nt] = __builtin_amdgcn_mfma_f32_16x16x32_bf16(bkh, qfh[k2], s_acc[nt], 0, 0, 0);
                s_acc[nt] = __builtin_amdgcn_mfma_f32_16x16x32_bf16(bkl, qfh[k2], s_acc[nt], 0, 0, 0);
                s_acc[nt] = __builtin_amdgcn_mfma_f32_16x16x32_bf16(bkh, qfl[k2], s_acc[nt], 0, 0, 0);
            }
        }

        // per-lane softmax over s (16 local vals + cross-quad shuffles)
        const unsigned long long word = msk64[(w << 4) + l15];
        const unsigned w0 = (unsigned)word;
        const unsigned w1 = (unsigned)(word >> 32);
        float sv[16];
        #pragma unroll
        for (int nt = 0; nt < 4; ++nt) {
            const unsigned wrd = (nt & 2) ? w1 : w0;
            #pragma unroll
            for (int reg = 0; reg < 4; ++reg) {
                const int bit = ((nt & 1) << 4) + (quad << 2) + reg;
                sv[nt * 4 + reg] = ((wrd >> bit) & 1u) ? s_acc[nt][reg] : NEGINF_F;
            }
        }
        float mx = sv[0];
        #pragma unroll
        for (int i = 1; i < 16; ++i) mx = fmaxf(mx, sv[i]);
        mx = fmaxf(mx, __shfl_xor(mx, 16));
        mx = fmaxf(mx, __shfl_xor(mx, 32));
        const float mnew  = fmaxf(m_i, mx);
        const float alpha = exp2f(m_i - mnew);   // exp2(-inf)=0 first tile
        float p[16], sum = 0.f;
        #pragma unroll
        for (int i = 0; i < 16; ++i) { p[i] = exp2f(sv[i] - mnew); sum += p[i]; }
        sum += __shfl_xor(sum, 16);
        sum += __shfl_xor(sum, 32);
        l_i = l_i * alpha + sum;
        m_i = mnew;
        #pragma unroll
        for (int nt = 0; nt < 4; ++nt) {
            O[nt][0] *= alpha; O[nt][1] *= alpha;
            O[nt][2] *= alpha; O[nt][3] *= alpha;
            bf16x4 pv = { (bf16)p[nt * 4 + 0], (bf16)p[nt * 4 + 1],
                          (bf16)p[nt * 4 + 2], (bf16)p[nt * 4 + 3] };
            *(bf16x4*)&Ps[w][l15][(nt << 4) + (quad << 2)] = pv;
        }

        // O^T += Vt P^T  (A=Vt rows h, B=P rows q)
        #pragma unroll
        for (int s2 = 0; s2 < 2; ++s2) {
            bf16x8 ap = *(const bf16x8*)&Ps[w][l15][(s2 << 5) + (quad << 3)];
            #pragma unroll
            for (int nt = 0; nt < 4; ++nt) {
                bf16x8 bv = *(const bf16x8*)&Vts[(nt << 4) + l15][(s2 << 5) + (quad << 3)];
                O[nt] = __builtin_amdgcn_mfma_f32_16x16x32_bf16(bv, ap, O[nt], 0, 0, 0);
            }
        }
    }

    // normalize + write AO (bf16, [B*T][N*H]); lane owns col q, rows h
    {
        const float inv = 1.0f / l_i;
        const size_t base = ((size_t)b * TT + qrow) * (NHD * HD) + (size_t)n * HD;
        #pragma unroll
        for (int nt = 0; nt < 4; ++nt) {
            bf16x4 o = { (bf16)(O[nt][0] * inv), (bf16)(O[nt][1] * inv),
                         (bf16)(O[nt][2] * inv), (bf16)(O[nt][3] * inv) };
            *(bf16x4*)(AO + base + (nt << 4) + (quad << 2)) = o;
        }
    }
}

// ---------------------------------------------------------------------------
extern "C" void kernel_launch(void* const* d_in, const int* in_sizes, int n_in,
                              void* d_out, int out_size, void* d_ws, size_t ws_size,
                              hipStream_t stream)
{
    const float* X   = (const float*)d_in[0];
    const int*   msk = (const int*)d_in[1];
    const float* wq  = (const float*)d_in[2];
    const float* bq  = (const float*)d_in[3];
    const float* wk  = (const float*)d_in[4];
    const float* bk  = (const float*)d_in[5];
    const float* wv  = (const float*)d_in[6];
    const float* bv  = (const float*)d_in[7];
    const float* wo  = (const float*)d_in[8];
    const float* bo  = (const float*)d_in[9];
    const float* pds = (const float*)d_in[10];
    float* out = (float*)d_out;

    bf16* ws   = (bf16*)d_ws;
    bf16* Xh   = ws;                      // 4M  (later aliased by AO)
    bf16* Xl   = ws + 4194304;            // 4M
    bf16* WQKh = ws + 8388608;            // 2M  [2048 nh'][1024 d]
    bf16* WQKl = ws + 10485760;           // 2M
    bf16* Wvh  = ws + 12582912;           // 1M  [nh][d]
    bf16* Wob  = ws + 13631488;           // 1M  [d][nh]
    bf16* Qhb  = ws + 14680064;           // 4M  [b][n][t][h]
    bf16* Qlb  = ws + 18874368;
    bf16* Khb  = ws + 23068672;
    bf16* Klb  = ws + 27262976;
    unsigned char* mbits = (unsigned char*)(ws + 31457280);   // 1 MB
    bf16* Vtb  = ws + 32505856;           // 4M [b][nh][t]
    bf16* AOb  = Xh;                      // alias: Xh dead after proj

    dim3 blk(256);

    prep_all<<<12288, blk, 0, stream>>>(X, msk, wq, wk, wv, wo,
                                        Xh, Xl, WQKh, WQKl, Wvh, Wob, mbits);

    // fused QK + V projections
    gemm_proj<<<768, blk, 0, stream>>>(
        Xh, Xl, WQKh, WQKl, Wvh, bq, bk, bv, pds,
        Qhb, Qlb, Khb, Klb, Vtb);

    dim3 ga(TT / 128, BB * NHD);   // (16, 32)
    attn_mfma<<<ga, dim3(512), 0, stream>>>(
        Qhb, Qlb, Khb, Klb, Vtb, (const unsigned long long*)mbits, AOb);

    // output projection: M=4096, N=1024, K=1024, fp32 out, 128x64 tiles
    gemm_out<<<dim3(16, 32), blk, 0, stream>>>(AOb, Wob, bo, out);
}